// Round 3
// baseline (269.332 us; speedup 1.0000x reference)
//
#include <hip/hip_runtime.h>
#include <hip/hip_bf16.h>
#include <hip/hip_fp16.h>

#define NPOS 784
#define WDIM 28

typedef _Float16 f16x8 __attribute__((ext_vector_type(8)));
typedef float    f32x4 __attribute__((ext_vector_type(4)));

// ---------------- kernel 1: merged embed + qkv ----------------
// Blocks 0..51: qkv. Block = (b, 64-ij tile); wave = m-group (4 m), h-loop inside.
//   All 16 m of every Q/K cache line are produced inside ONE block (one XCD) ->
//   full-line dirtying, no cross-XCD false sharing (r2: 16 blocks/line, ~16x WRITE amp).
// Block 52: embedding-MLP tables Etr/Etc (transposed [m][110]).
// Block 53: zero the Vfrag key-pad region (keys 784..831).
__global__ __launch_bounds__(256) void prep_kernel(
    const float* __restrict__ x,
    const float* __restrict__ wq, const float* __restrict__ bq,
    const float* __restrict__ wk, const float* __restrict__ bk,
    const float* __restrict__ wv, const float* __restrict__ bv,
    const float* __restrict__ rw1, const float* __restrict__ rb1,
    const float* __restrict__ rga, const float* __restrict__ rbe,
    const float* __restrict__ rw2, const float* __restrict__ rb2,
    const float* __restrict__ cw1, const float* __restrict__ cb1,
    const float* __restrict__ cga, const float* __restrict__ cbe,
    const float* __restrict__ cw2, const float* __restrict__ cb2,
    float* __restrict__ Q, float* __restrict__ K, _Float16* __restrict__ Vfrag,
    float* __restrict__ Etr, float* __restrict__ Etc)
{
    const int t = threadIdx.x;
    if (blockIdx.x == 52) {                          // ---- embed path ----
        int d = -1;
        const float *w1 = rw1, *b1 = rb1, *ga = rga, *be = rbe, *w2 = rw2, *b2 = rb2;
        float* E = Etr;
        if (t < 110) { d = t; }
        else if (t >= 128 && t < 238) { d = t - 128; w1 = cw1; b1 = cb1; ga = cga; be = cbe; w2 = cw2; b2 = cb2; E = Etc; }
        if (d < 0) return;
        float u = (d < 55) ? (-1.0f + (float)d * (2.0f / 54.0f))
                           : -(-1.0f + (float)(d - 55) * (2.0f / 54.0f));
        float hb[16], mu = 0.0f;
#pragma unroll
        for (int c = 0; c < 16; ++c) { hb[c] = u * w1[c] + b1[c]; mu += hb[c]; }
        mu *= (1.0f / 16.0f);
        float var = 0.0f;
#pragma unroll
        for (int c = 0; c < 16; ++c) { float dv = hb[c] - mu; var += dv * dv; }
        var *= (1.0f / 16.0f);
        float rstd = rsqrtf(var + 1e-5f);
#pragma unroll
        for (int c = 0; c < 16; ++c) {
            float hn = ga[c] * (hb[c] - mu) * rstd + be[c];
            hb[c] = hn / (1.0f + __expf(-hn));
        }
#pragma unroll
        for (int m = 0; m < 8; ++m) {
            float e = b2[m];
#pragma unroll
            for (int c = 0; c < 16; ++c) e += hb[c] * w2[m * 16 + c];
            E[m * 110 + d] = e;
        }
        return;
    }

    if (blockIdx.x == 53) {                          // ---- Vfrag pad-zero path ----
        // pad keys 784..831: step 24 fragment-lanes 32..63 + step 25 all lanes.
        unsigned int* pz = (unsigned int*)Vfrag;
        for (int e = t; e < 32 * 384; e += 256) {
            int bh = e / 384, r = e - bh * 384;
            int idx;
            if (r < 128) idx = ((bh * 26 + 24) * 64 + 32 + (r >> 2)) * 4 + (r & 3);
            else { int rr = r - 128; idx = ((bh * 26 + 25) * 64 + (rr >> 2)) * 4 + (rr & 3); }
            pz[idx] = 0u;
        }
        return;
    }

    // ---- qkv path: blocks 0..51 = (b, ij-tile of 64) ----
    const int bid  = blockIdx.x;
    const int b    = bid / 13, tile = bid - b * 13;
    const int lane = t & 63, mg = t >> 6;            // wave = m-group {4mg..4mg+3}
    const int ij   = tile * 64 + lane;
    if (ij >= NPOS) return;

    float x0 = x[(b * 3 + 0) * NPOS + ij];
    float x1 = x[(b * 3 + 1) * NPOS + ij];
    float x2 = x[(b * 3 + 2) * NPOS + ij];

    const int kk = ij & 31, s5 = ij >> 5;
    const int flbase = (kk >> 3) << 4;
#pragma unroll
    for (int h = 0; h < 8; ++h) {
        float4 qv, kv;
        float vv[4];
#pragma unroll
        for (int j = 0; j < 4; ++j) {
            int m = mg * 4 + j, oc = m * 8 + h;      // wave-uniform -> scalar loads
            float w0, w1, w2v;
            w0 = wq[oc*3+0]; w1 = wq[oc*3+1]; w2v = wq[oc*3+2];
            ((float*)&qv)[j] = bq[oc] + w0*x0 + w1*x1 + w2v*x2;
            w0 = wk[oc*3+0]; w1 = wk[oc*3+1]; w2v = wk[oc*3+2];
            ((float*)&kv)[j] = bk[oc] + w0*x0 + w1*x1 + w2v*x2;
            w0 = wv[oc*3+0]; w1 = wv[oc*3+1]; w2v = wv[oc*3+2];
            vv[j] = bv[oc] + w0*x0 + w1*x1 + w2v*x2;
        }
        const int bh = b * 8 + h;
        *(float4*)(Q + ((size_t)(bh * NPOS + ij)) * 16 + mg * 4) = qv;
        *(float4*)(K + ((size_t)(bh * NPOS + ij)) * 16 + mg * 4) = kv;
        // V fragment: element ((bh*26+s5)*64 + flbase|m)*8 + (kk&7); +8 halves per m
        _Float16* vb = Vfrag + ((((size_t)bh * 26 + s5) * 64 + flbase) << 3) + (kk & 7);
#pragma unroll
        for (int j = 0; j < 4; ++j) vb[(mg * 4 + j) * 8] = (_Float16)vv[j];
    }
}

// ---------------- kernel 2: attention, 8 heads per block (512 threads) ----------------
// Grid = 3136 blocks (b, ij), XCD-chunked swizzle. One head per wave.
// r3 change: epilogue writes COALESCED out_t[b][ij][og] (1KB/block contiguous)
// instead of 256 scattered 4B stores (r2: 113MB WRITE_SIZE vs 3.2MB output).
// Final layout produced by trans_kernel. direct=1 falls back to scattered stores.
__global__ __launch_bounds__(512, 8) void attn_kernel(
    const float* __restrict__ Q, const float* __restrict__ K,
    const _Float16* __restrict__ Vfrag,
    const float* __restrict__ Etr, const float* __restrict__ Etc,
    const float* __restrict__ w_out, const float* __restrict__ b_out,
    float* __restrict__ out_t, float* __restrict__ out, int direct)
{
    __shared__ float4 RtE[8][56];                         // exp'ed rotation terms / wave
    __shared__ __align__(16) _Float16 ptile[8][320];      // [wave][g*80 + k], 64 keys/chunk
    __shared__ float ovs[4 * 132];                        // [g][m*8+h], g-stride 132

    const int t    = threadIdx.x;
    const int wave = t >> 6, lane = t & 63;
    // XCD-chunked decode: each XCD owns a contiguous run of (b, ij)
    const int bid = blockIdx.x;
    const int g   = (bid & 7) * 392 + (bid >> 3);         // bijective, 3136 = 8*392
    const int b   = g / 784;
    const int ij  = g - b * 784;
    const int iq  = ij / WDIM, jq = ij % WDIM;
    const int bh  = b * 8 + wave;                         // head = wave
    const float scale = 0.57735026918962576f;             // 1/sqrt(CIN=3)

    // q in registers (wave-uniform loads, L2-hot)
    float q[16];
    {
        const float4* qp = (const float4*)(Q + (size_t)(bh * NPOS + ij) * 16);
        float4 q0 = qp[0], q1 = qp[1], q2 = qp[2], q3 = qp[3];
        q[0]=q0.x; q[1]=q0.y; q[2]=q0.z; q[3]=q0.w;
        q[4]=q1.x; q[5]=q1.y; q[6]=q1.z; q[7]=q1.w;
        q[8]=q2.x; q[9]=q2.y; q[10]=q2.z; q[11]=q2.w;
        q[12]=q3.x; q[13]=q3.y; q[14]=q3.z; q[15]=q3.w;
    }

    // rotation terms from global tables -> exp'ed
    {
        float4 mine = make_float4(-3.0e38f, -3.0e38f, -3.0e38f, -3.0e38f);
        float4 rv   = mine;
        if (lane < 55) {
            float ar = 0, ac = 0, ar5 = 0, ac5 = 0;
#pragma unroll
            for (int mm = 0; mm < 8; ++mm) {
                float ql = q[mm], qh = q[8 + mm];
                ar  += ql * Etr[mm * 110 + lane];
                ar5 += ql * Etr[mm * 110 + lane + 55];
                ac  += qh * Etc[mm * 110 + lane];
                ac5 += qh * Etc[mm * 110 + lane + 55];
            }
            rv = make_float4(ar * scale, ac * scale, ar5 * scale, ac5 * scale);
            mine = rv;
        }
#pragma unroll
        for (int off = 1; off < 64; off <<= 1) {
            mine.x = fmaxf(mine.x, __shfl_xor(mine.x, off, 64));
            mine.y = fmaxf(mine.y, __shfl_xor(mine.y, off, 64));
            mine.z = fmaxf(mine.z, __shfl_xor(mine.z, off, 64));
            mine.w = fmaxf(mine.w, __shfl_xor(mine.w, off, 64));
        }
        if (lane < 55)
            RtE[wave][lane] = make_float4(__expf(rv.x - mine.x), __expf(rv.y - mine.y),
                                          __expf(rv.z - mine.z), __expf(rv.w - mine.w));
    }

    // pass A: content in registers; track max
    float creg[13];
    float maxc = -3.0e38f;
#pragma unroll
    for (int it = 0; it < 13; ++it) {
        int k = it * 64 + lane;
        creg[it] = 0.0f;
        if (k < NPOS) {
            const float4* kp = (const float4*)(K + (size_t)(bh * NPOS + k) * 16);
            float4 k0 = kp[0], k1 = kp[1], k2 = kp[2], k3 = kp[3];
            float c = q[0]*k0.x + q[1]*k0.y + q[2]*k0.z + q[3]*k0.w
                    + q[4]*k1.x + q[5]*k1.y + q[6]*k1.z + q[7]*k1.w
                    + q[8]*k2.x + q[9]*k2.y + q[10]*k2.z + q[11]*k2.w
                    + q[12]*k3.x + q[13]*k3.y + q[14]*k3.z + q[15]*k3.w;
            creg[it] = c * scale;
            maxc = fmaxf(maxc, creg[it]);
        }
    }
#pragma unroll
    for (int off = 1; off < 64; off <<= 1) maxc = fmaxf(maxc, __shfl_xor(maxc, off, 64));

    // pass B+C interleaved: per 64-key chunk, compute p -> tiny LDS tile ->
    // 2x v_mfma_f32_16x16x32_f16. No barriers (ptile is wave-private).
    float ps0 = 0, ps1 = 0, ps2 = 0, ps3 = 0;
    f32x4 d = {0.0f, 0.0f, 0.0f, 0.0f};
    {
        const int g15 = lane & 15, kg = lane >> 4;
        _Float16* pt = &ptile[wave][0];                   // rows at g*80 halves
        const _Float16* ar0 = &ptile[wave][g15 * 80 + kg * 8];
        const f16x8* vp = (const f16x8*)(Vfrag + ((size_t)bh * 26 * 64 + lane) * 8);
#pragma unroll
        for (int c = 0; c < 13; ++c) {
            int k = c * 64 + lane;
            float p0 = 0.0f, p1 = 0.0f, p2 = 0.0f, p3 = 0.0f;
            if (k < NPOS) {
                float ec = __expf(creg[c] - maxc);
                int rk = (k * 2341) >> 16;                // k / 28 (exact for k < 784)
                int ck = k - rk * WDIM;
                float4 er = RtE[wave][rk - iq + 27];
                float4 el = RtE[wave][ck - jq + 27];
                p0 = ec * er.x * el.y;
                p1 = ec * er.y * el.z;
                p2 = ec * er.z * el.w;
                p3 = ec * er.w * el.x;
                ps0 += p0; ps1 += p1; ps2 += p2; ps3 += p3;
            }
            pt[0 * 80 + lane] = (_Float16)p0;             // pad keys write exact zeros
            pt[1 * 80 + lane] = (_Float16)p1;
            pt[2 * 80 + lane] = (_Float16)p2;
            pt[3 * 80 + lane] = (_Float16)p3;
#pragma unroll
            for (int s2 = 0; s2 < 2; ++s2) {
                f16x8 a = {};
                if (g15 < 4) a = *(const f16x8*)(ar0 + s2 * 32);
                f16x8 bf = vp[(c * 2 + s2) * 64];
                d = __builtin_amdgcn_mfma_f32_16x16x32_f16(a, bf, d, 0, 0, 0);
            }
        }
    }
#pragma unroll
    for (int off = 1; off < 64; off <<= 1) {
        ps0 += __shfl_xor(ps0, off, 64); ps1 += __shfl_xor(ps1, off, 64);
        ps2 += __shfl_xor(ps2, off, 64); ps3 += __shfl_xor(ps3, off, 64);
    }

    // D layout (verified): col=lane&15 (=m), row=(lane>>4)*4+reg (=g) -> lanes 0..15
    if ((lane >> 4) == 0) {
        float i0 = 1.0f / ps0, i1 = 1.0f / ps1, i2 = 1.0f / ps2, i3 = 1.0f / ps3;
        ovs[0 * 132 + lane * 8 + wave] = d[0] * i0;
        ovs[1 * 132 + lane * 8 + wave] = d[1] * i1;
        ovs[2 * 132 + lane * 8 + wave] = d[2] * i2;
        ovs[3 * 132 + lane * 8 + wave] = d[3] * i3;
    }
    __syncthreads();                                      // all 8 heads ready

    // output projection; thread = (o = t>>2, g = t&3), t < 256
    if (t < 256) {
        int o = t >> 2, gg = t & 3;
        float a = 0.0f;
#pragma unroll
        for (int i = 0; i < 32; ++i) {
            float4 w4 = *(const float4*)(w_out + o * 128 + i * 4);
            float4 ov = *(const float4*)(ovs + gg * 132 + i * 4);
            a += w4.x * ov.x + w4.y * ov.y + w4.z * ov.z + w4.w * ov.w;
        }
        a += b_out[o];
        if (direct)
            out[((size_t)(b * 64 + o) * 4 + gg) * NPOS + ij] = a;
        else
            out_t[((size_t)(b * NPOS + ij)) * 256 + t] = a;  // 1KB contiguous / block
    }
}

// ---------------- kernel 3: tiled transpose [b][ij][og] -> [b][og][ij] ----------------
// Grid = 4b x 4 og-tiles x 13 ij-tiles = 208 blocks. Coalesced both sides.
__global__ __launch_bounds__(256) void trans_kernel(
    const float* __restrict__ out_t, float* __restrict__ out)
{
    __shared__ float tile[64 * 65];
    const int bid = blockIdx.x;
    const int ijt = bid % 13, rest = bid / 13;
    const int ogt = rest & 3, b = rest >> 2;
    const int t = threadIdx.x;
    const int c = t & 63, r = t >> 6;
    const int ij0 = ijt * 64, og0 = ogt * 64;
#pragma unroll
    for (int rr = 0; rr < 16; ++rr) {
        int row = rr * 4 + r;                             // ij_local
        int ij = ij0 + row;
        float v = 0.0f;
        if (ij < NPOS) v = out_t[((size_t)b * NPOS + ij) * 256 + og0 + c];
        tile[c * 65 + row] = v;
    }
    __syncthreads();
#pragma unroll
    for (int rr = 0; rr < 16; ++rr) {
        int ogl = rr * 4 + r;
        int ij = ij0 + c;
        if (ij < NPOS)
            out[((size_t)(b * 256 + og0 + ogl)) * NPOS + ij] = tile[ogl * 65 + c];
    }
}

extern "C" void kernel_launch(void* const* d_in, const int* in_sizes, int n_in,
                              void* d_out, int out_size, void* d_ws, size_t ws_size,
                              hipStream_t stream)
{
    const float* x     = (const float*)d_in[0];
    const float* wq    = (const float*)d_in[1];
    const float* bq    = (const float*)d_in[2];
    const float* wk    = (const float*)d_in[3];
    const float* bk    = (const float*)d_in[4];
    const float* wv    = (const float*)d_in[5];
    const float* bv    = (const float*)d_in[6];
    const float* w_out = (const float*)d_in[7];
    const float* b_out = (const float*)d_in[8];
    const float* rw1 = (const float*)d_in[9];
    const float* rb1 = (const float*)d_in[10];
    const float* rga = (const float*)d_in[11];
    const float* rbe = (const float*)d_in[12];
    const float* rw2 = (const float*)d_in[13];
    const float* rb2 = (const float*)d_in[14];
    const float* cw1 = (const float*)d_in[15];
    const float* cb1 = (const float*)d_in[16];
    const float* cga = (const float*)d_in[17];
    const float* cbe = (const float*)d_in[18];
    const float* cw2 = (const float*)d_in[19];
    const float* cb2 = (const float*)d_in[20];
    // d_in[21]/d_in[22] (ridx/cidx) unused: closed-form rotation indices.

    float* Q   = (float*)d_ws;               // 3.2MB Q/K + tables + Vfrag + out_t
    float* K   = Q + 401408;
    float* Etr = K + 401408;                 // 880 floats
    float* Etc = Etr + 880;                  // 880 floats
    _Float16* Vfrag = (_Float16*)(Etc + 880);// 32*26*64*8 = 425984 halves (16B-aligned)
    float* out_t = (float*)(Vfrag + 425984); // 4*784*256 floats = 3.2MB

    const size_t ws_needed = (size_t)(2 * 401408 + 1760) * 4 + 425984 * 2
                           + (size_t)4 * NPOS * 256 * 4;
    const int direct = (ws_size < ws_needed) ? 1 : 0;     // fallback: scattered stores

    prep_kernel<<<54, 256, 0, stream>>>(x, wq, bq, wk, bk, wv, bv,
                                        rw1, rb1, rga, rbe, rw2, rb2,
                                        cw1, cb1, cga, cbe, cw2, cb2,
                                        Q, K, Vfrag, Etr, Etc);
    attn_kernel<<<4 * NPOS, 512, 0, stream>>>(
        Q, K, Vfrag, Etr, Etc, w_out, b_out, out_t, (float*)d_out, direct);
    if (!direct)
        trans_kernel<<<208, 256, 0, stream>>>(out_t, (float*)d_out);
}

// Round 4
// 253.557 us; speedup vs baseline: 1.0622x; 1.0622x over previous
//
#include <hip/hip_runtime.h>
#include <hip/hip_bf16.h>
#include <hip/hip_fp16.h>

#define NPOS 784
#define WDIM 28

typedef _Float16 f16x8 __attribute__((ext_vector_type(8)));
typedef float    f32x4 __attribute__((ext_vector_type(4)));

// ---------------- kernel 1: merged embed + qkv ----------------
// Blocks 0..415: qkv. Block = (b, 64-ij tile, h); wave = m-group (4 m).
//   All 16 m of every Q/K cache line are produced inside ONE block ->
//   full-line dirtying, no cross-XCD false sharing.
// Block 416: embedding-MLP tables Etr/Etc (transposed [m][110]).
// Block 417: zero the Vfrag key-pad region (keys 784..831).
__global__ __launch_bounds__(256) void prep_kernel(
    const float* __restrict__ x,
    const float* __restrict__ wq, const float* __restrict__ bq,
    const float* __restrict__ wk, const float* __restrict__ bk,
    const float* __restrict__ wv, const float* __restrict__ bv,
    const float* __restrict__ rw1, const float* __restrict__ rb1,
    const float* __restrict__ rga, const float* __restrict__ rbe,
    const float* __restrict__ rw2, const float* __restrict__ rb2,
    const float* __restrict__ cw1, const float* __restrict__ cb1,
    const float* __restrict__ cga, const float* __restrict__ cbe,
    const float* __restrict__ cw2, const float* __restrict__ cb2,
    float* __restrict__ Q, float* __restrict__ K, _Float16* __restrict__ Vfrag,
    float* __restrict__ Etr, float* __restrict__ Etc)
{
    const int t = threadIdx.x;
    if (blockIdx.x == 416) {                         // ---- embed path ----
        int d = -1;
        const float *w1 = rw1, *b1 = rb1, *ga = rga, *be = rbe, *w2 = rw2, *b2 = rb2;
        float* E = Etr;
        if (t < 110) { d = t; }
        else if (t >= 128 && t < 238) { d = t - 128; w1 = cw1; b1 = cb1; ga = cga; be = cbe; w2 = cw2; b2 = cb2; E = Etc; }
        if (d < 0) return;
        float u = (d < 55) ? (-1.0f + (float)d * (2.0f / 54.0f))
                           : -(-1.0f + (float)(d - 55) * (2.0f / 54.0f));
        float hb[16], mu = 0.0f;
#pragma unroll
        for (int c = 0; c < 16; ++c) { hb[c] = u * w1[c] + b1[c]; mu += hb[c]; }
        mu *= (1.0f / 16.0f);
        float var = 0.0f;
#pragma unroll
        for (int c = 0; c < 16; ++c) { float dv = hb[c] - mu; var += dv * dv; }
        var *= (1.0f / 16.0f);
        float rstd = rsqrtf(var + 1e-5f);
#pragma unroll
        for (int c = 0; c < 16; ++c) {
            float hn = ga[c] * (hb[c] - mu) * rstd + be[c];
            hb[c] = hn / (1.0f + __expf(-hn));
        }
#pragma unroll
        for (int m = 0; m < 8; ++m) {
            float e = b2[m];
#pragma unroll
            for (int c = 0; c < 16; ++c) e += hb[c] * w2[m * 16 + c];
            E[m * 110 + d] = e;
        }
        return;
    }

    if (blockIdx.x == 417) {                         // ---- Vfrag pad-zero path ----
        // pad keys 784..831: step 24 fragment-lanes 32..63 + step 25 all lanes.
        unsigned int* pz = (unsigned int*)Vfrag;
        for (int e = t; e < 32 * 384; e += 256) {
            int bh = e / 384, r = e - bh * 384;
            int idx;
            if (r < 128) idx = ((bh * 26 + 24) * 64 + 32 + (r >> 2)) * 4 + (r & 3);
            else { int rr = r - 128; idx = ((bh * 26 + 25) * 64 + (rr >> 2)) * 4 + (rr & 3); }
            pz[idx] = 0u;
        }
        return;
    }

    // ---- qkv path: blocks 0..415 = (b, ij-tile of 64, h) ----
    const int bid  = blockIdx.x;
    const int b    = bid / 104, rem = bid - b * 104;
    const int tile = rem >> 3, h = rem & 7;
    const int lane = t & 63, mg = t >> 6;            // wave = m-group {4mg..4mg+3}
    const int ij   = tile * 64 + lane;
    if (ij >= NPOS) return;

    float x0 = x[(b * 3 + 0) * NPOS + ij];
    float x1 = x[(b * 3 + 1) * NPOS + ij];
    float x2 = x[(b * 3 + 2) * NPOS + ij];

    const int kk = ij & 31, s5 = ij >> 5;
    const int flbase = (kk >> 3) << 4;
    float4 qv, kv;
    float vv[4];
#pragma unroll
    for (int j = 0; j < 4; ++j) {
        int m = mg * 4 + j, oc = m * 8 + h;          // wave-uniform weight loads
        float w0, w1, w2v;
        w0 = wq[oc*3+0]; w1 = wq[oc*3+1]; w2v = wq[oc*3+2];
        ((float*)&qv)[j] = bq[oc] + w0*x0 + w1*x1 + w2v*x2;
        w0 = wk[oc*3+0]; w1 = wk[oc*3+1]; w2v = wk[oc*3+2];
        ((float*)&kv)[j] = bk[oc] + w0*x0 + w1*x1 + w2v*x2;
        w0 = wv[oc*3+0]; w1 = wv[oc*3+1]; w2v = wv[oc*3+2];
        vv[j] = bv[oc] + w0*x0 + w1*x1 + w2v*x2;
    }
    const int bh = b * 8 + h;
    *(float4*)(Q + ((size_t)(bh * NPOS + ij)) * 16 + mg * 4) = qv;
    *(float4*)(K + ((size_t)(bh * NPOS + ij)) * 16 + mg * 4) = kv;
    // V fragment: element ((bh*26+s5)*64 + flbase|m)*8 + (kk&7)
    _Float16* vb = Vfrag + ((((size_t)bh * 26 + s5) * 64 + flbase) << 3) + (kk & 7);
#pragma unroll
    for (int j = 0; j < 4; ++j) vb[(mg * 4 + j) * 8] = (_Float16)vv[j];
}

// ---------------- kernel 2: attention, 8 heads per block (512 threads) ----------------
// Grid = 3136 blocks (b, ij), XCD-chunked swizzle. One head per wave.
// r4 change: __launch_bounds__(512, 6) (was (512,8)). The 8-waves/EU bound
// capped VGPRs at 64 -> compiler spilled q[16]/creg[13] to scratch -> ~180MB
// of HBM spill traffic (r3: FETCH 63MB / WRITE 126MB vs ~10MB true footprint).
// 6 waves/EU = 85 VGPR budget = no spill; 75% occupancy (= what HW delivered).
__global__ __launch_bounds__(512, 6) void attn_kernel(
    const float* __restrict__ Q, const float* __restrict__ K,
    const _Float16* __restrict__ Vfrag,
    const float* __restrict__ Etr, const float* __restrict__ Etc,
    const float* __restrict__ w_out, const float* __restrict__ b_out,
    float* __restrict__ out_t, float* __restrict__ out, int direct)
{
    __shared__ float4 RtE[8][56];                         // exp'ed rotation terms / wave
    __shared__ __align__(16) _Float16 ptile[8][320];      // [wave][g*80 + k], 64 keys/chunk
    __shared__ float ovs[4 * 132];                        // [g][m*8+h], g-stride 132

    const int t    = threadIdx.x;
    const int wave = t >> 6, lane = t & 63;
    // XCD-chunked decode: each XCD owns a contiguous run of (b, ij)
    const int bid = blockIdx.x;
    const int g   = (bid & 7) * 392 + (bid >> 3);         // bijective, 3136 = 8*392
    const int b   = g / 784;
    const int ij  = g - b * 784;
    const int iq  = ij / WDIM, jq = ij % WDIM;
    const int bh  = b * 8 + wave;                         // head = wave
    const float scale = 0.57735026918962576f;             // 1/sqrt(CIN=3)

    // q in registers (wave-uniform loads, L2-hot)
    float q[16];
    {
        const float4* qp = (const float4*)(Q + (size_t)(bh * NPOS + ij) * 16);
        float4 q0 = qp[0], q1 = qp[1], q2 = qp[2], q3 = qp[3];
        q[0]=q0.x; q[1]=q0.y; q[2]=q0.z; q[3]=q0.w;
        q[4]=q1.x; q[5]=q1.y; q[6]=q1.z; q[7]=q1.w;
        q[8]=q2.x; q[9]=q2.y; q[10]=q2.z; q[11]=q2.w;
        q[12]=q3.x; q[13]=q3.y; q[14]=q3.z; q[15]=q3.w;
    }

    // rotation terms from global tables -> exp'ed
    {
        float4 mine = make_float4(-3.0e38f, -3.0e38f, -3.0e38f, -3.0e38f);
        float4 rv   = mine;
        if (lane < 55) {
            float ar = 0, ac = 0, ar5 = 0, ac5 = 0;
#pragma unroll
            for (int mm = 0; mm < 8; ++mm) {
                float ql = q[mm], qh = q[8 + mm];
                ar  += ql * Etr[mm * 110 + lane];
                ar5 += ql * Etr[mm * 110 + lane + 55];
                ac  += qh * Etc[mm * 110 + lane];
                ac5 += qh * Etc[mm * 110 + lane + 55];
            }
            rv = make_float4(ar * scale, ac * scale, ar5 * scale, ac5 * scale);
            mine = rv;
        }
#pragma unroll
        for (int off = 1; off < 64; off <<= 1) {
            mine.x = fmaxf(mine.x, __shfl_xor(mine.x, off, 64));
            mine.y = fmaxf(mine.y, __shfl_xor(mine.y, off, 64));
            mine.z = fmaxf(mine.z, __shfl_xor(mine.z, off, 64));
            mine.w = fmaxf(mine.w, __shfl_xor(mine.w, off, 64));
        }
        if (lane < 55)
            RtE[wave][lane] = make_float4(__expf(rv.x - mine.x), __expf(rv.y - mine.y),
                                          __expf(rv.z - mine.z), __expf(rv.w - mine.w));
    }

    // pass A: content in registers; track max
    float creg[13];
    float maxc = -3.0e38f;
#pragma unroll
    for (int it = 0; it < 13; ++it) {
        int k = it * 64 + lane;
        creg[it] = 0.0f;
        if (k < NPOS) {
            const float4* kp = (const float4*)(K + (size_t)(bh * NPOS + k) * 16);
            float4 k0 = kp[0], k1 = kp[1], k2 = kp[2], k3 = kp[3];
            float c = q[0]*k0.x + q[1]*k0.y + q[2]*k0.z + q[3]*k0.w
                    + q[4]*k1.x + q[5]*k1.y + q[6]*k1.z + q[7]*k1.w
                    + q[8]*k2.x + q[9]*k2.y + q[10]*k2.z + q[11]*k2.w
                    + q[12]*k3.x + q[13]*k3.y + q[14]*k3.z + q[15]*k3.w;
            creg[it] = c * scale;
            maxc = fmaxf(maxc, creg[it]);
        }
    }
#pragma unroll
    for (int off = 1; off < 64; off <<= 1) maxc = fmaxf(maxc, __shfl_xor(maxc, off, 64));

    // pass B+C interleaved: per 64-key chunk, compute p -> tiny LDS tile ->
    // 2x v_mfma_f32_16x16x32_f16. No barriers (ptile is wave-private).
    float ps0 = 0, ps1 = 0, ps2 = 0, ps3 = 0;
    f32x4 d = {0.0f, 0.0f, 0.0f, 0.0f};
    {
        const int g15 = lane & 15, kg = lane >> 4;
        _Float16* pt = &ptile[wave][0];                   // rows at g*80 halves
        const _Float16* ar0 = &ptile[wave][g15 * 80 + kg * 8];
        const f16x8* vp = (const f16x8*)(Vfrag + ((size_t)bh * 26 * 64 + lane) * 8);
#pragma unroll
        for (int c = 0; c < 13; ++c) {
            int k = c * 64 + lane;
            float p0 = 0.0f, p1 = 0.0f, p2 = 0.0f, p3 = 0.0f;
            if (k < NPOS) {
                float ec = __expf(creg[c] - maxc);
                int rk = (k * 2341) >> 16;                // k / 28 (exact for k < 784)
                int ck = k - rk * WDIM;
                float4 er = RtE[wave][rk - iq + 27];
                float4 el = RtE[wave][ck - jq + 27];
                p0 = ec * er.x * el.y;
                p1 = ec * er.y * el.z;
                p2 = ec * er.z * el.w;
                p3 = ec * er.w * el.x;
                ps0 += p0; ps1 += p1; ps2 += p2; ps3 += p3;
            }
            pt[0 * 80 + lane] = (_Float16)p0;             // pad keys write exact zeros
            pt[1 * 80 + lane] = (_Float16)p1;
            pt[2 * 80 + lane] = (_Float16)p2;
            pt[3 * 80 + lane] = (_Float16)p3;
#pragma unroll
            for (int s2 = 0; s2 < 2; ++s2) {
                f16x8 a = {};
                if (g15 < 4) a = *(const f16x8*)(ar0 + s2 * 32);
                f16x8 bf = vp[(c * 2 + s2) * 64];
                d = __builtin_amdgcn_mfma_f32_16x16x32_f16(a, bf, d, 0, 0, 0);
            }
        }
    }
#pragma unroll
    for (int off = 1; off < 64; off <<= 1) {
        ps0 += __shfl_xor(ps0, off, 64); ps1 += __shfl_xor(ps1, off, 64);
        ps2 += __shfl_xor(ps2, off, 64); ps3 += __shfl_xor(ps3, off, 64);
    }

    // D layout (verified): col=lane&15 (=m), row=(lane>>4)*4+reg (=g) -> lanes 0..15
    if ((lane >> 4) == 0) {
        float i0 = 1.0f / ps0, i1 = 1.0f / ps1, i2 = 1.0f / ps2, i3 = 1.0f / ps3;
        ovs[0 * 132 + lane * 8 + wave] = d[0] * i0;
        ovs[1 * 132 + lane * 8 + wave] = d[1] * i1;
        ovs[2 * 132 + lane * 8 + wave] = d[2] * i2;
        ovs[3 * 132 + lane * 8 + wave] = d[3] * i3;
    }
    __syncthreads();                                      // all 8 heads ready

    // output projection; thread = (o = t>>2, g = t&3), t < 256
    if (t < 256) {
        int o = t >> 2, gg = t & 3;
        float a = 0.0f;
#pragma unroll
        for (int i = 0; i < 32; ++i) {
            float4 w4 = *(const float4*)(w_out + o * 128 + i * 4);
            float4 ov = *(const float4*)(ovs + gg * 132 + i * 4);
            a += w4.x * ov.x + w4.y * ov.y + w4.z * ov.z + w4.w * ov.w;
        }
        a += b_out[o];
        if (direct)
            out[((size_t)(b * 64 + o) * 4 + gg) * NPOS + ij] = a;
        else
            out_t[((size_t)(b * NPOS + ij)) * 256 + t] = a;  // 1KB contiguous / block
    }
}

// ---------------- kernel 3: tiled transpose [b][ij][og] -> [b][og][ij] ----------------
// Grid = 4b x 4 og-tiles x 13 ij-tiles = 208 blocks. Coalesced both sides.
__global__ __launch_bounds__(256) void trans_kernel(
    const float* __restrict__ out_t, float* __restrict__ out)
{
    __shared__ float tile[64 * 65];
    const int bid = blockIdx.x;
    const int ijt = bid % 13, rest = bid / 13;
    const int ogt = rest & 3, b = rest >> 2;
    const int t = threadIdx.x;
    const int c = t & 63, r = t >> 6;
    const int ij0 = ijt * 64, og0 = ogt * 64;
#pragma unroll
    for (int rr = 0; rr < 16; ++rr) {
        int row = rr * 4 + r;                             // ij_local
        int ij = ij0 + row;
        float v = 0.0f;
        if (ij < NPOS) v = out_t[((size_t)b * NPOS + ij) * 256 + og0 + c];
        tile[c * 65 + row] = v;
    }
    __syncthreads();
#pragma unroll
    for (int rr = 0; rr < 16; ++rr) {
        int ogl = rr * 4 + r;
        int ij = ij0 + c;
        if (ij < NPOS)
            out[((size_t)(b * 256 + og0 + ogl)) * NPOS + ij] = tile[ogl * 65 + c];
    }
}

extern "C" void kernel_launch(void* const* d_in, const int* in_sizes, int n_in,
                              void* d_out, int out_size, void* d_ws, size_t ws_size,
                              hipStream_t stream)
{
    const float* x     = (const float*)d_in[0];
    const float* wq    = (const float*)d_in[1];
    const float* bq    = (const float*)d_in[2];
    const float* wk    = (const float*)d_in[3];
    const float* bk    = (const float*)d_in[4];
    const float* wv    = (const float*)d_in[5];
    const float* bv    = (const float*)d_in[6];
    const float* w_out = (const float*)d_in[7];
    const float* b_out = (const float*)d_in[8];
    const float* rw1 = (const float*)d_in[9];
    const float* rb1 = (const float*)d_in[10];
    const float* rga = (const float*)d_in[11];
    const float* rbe = (const float*)d_in[12];
    const float* rw2 = (const float*)d_in[13];
    const float* rb2 = (const float*)d_in[14];
    const float* cw1 = (const float*)d_in[15];
    const float* cb1 = (const float*)d_in[16];
    const float* cga = (const float*)d_in[17];
    const float* cbe = (const float*)d_in[18];
    const float* cw2 = (const float*)d_in[19];
    const float* cb2 = (const float*)d_in[20];
    // d_in[21]/d_in[22] (ridx/cidx) unused: closed-form rotation indices.

    float* Q   = (float*)d_ws;               // 3.2MB Q/K + tables + Vfrag + out_t
    float* K   = Q + 401408;
    float* Etr = K + 401408;                 // 880 floats
    float* Etc = Etr + 880;                  // 880 floats
    _Float16* Vfrag = (_Float16*)(Etc + 880);// 32*26*64*8 = 425984 halves (16B-aligned)
    float* out_t = (float*)(Vfrag + 425984); // 4*784*256 floats = 3.2MB

    const size_t ws_needed = (size_t)(2 * 401408 + 1760) * 4 + 425984 * 2
                           + (size_t)4 * NPOS * 256 * 4;
    const int direct = (ws_size < ws_needed) ? 1 : 0;     // fallback: scattered stores

    prep_kernel<<<418, 256, 0, stream>>>(x, wq, bq, wk, bk, wv, bv,
                                         rw1, rb1, rga, rbe, rw2, rb2,
                                         cw1, cb1, cga, cbe, cw2, cb2,
                                         Q, K, Vfrag, Etr, Etc);
    attn_kernel<<<4 * NPOS, 512, 0, stream>>>(
        Q, K, Vfrag, Etr, Etc, w_out, b_out, out_t, (float*)d_out, direct);
    if (!direct)
        trans_kernel<<<208, 256, 0, stream>>>(out_t, (float*)d_out);
}

// Round 6
// 190.303 us; speedup vs baseline: 1.4153x; 1.3324x over previous
//
#include <hip/hip_runtime.h>
#include <hip/hip_fp16.h>

#define NPOS 784
#define WDIM 28

typedef _Float16 f16x8 __attribute__((ext_vector_type(8)));
typedef _Float16 f16x4 __attribute__((ext_vector_type(4)));
typedef float    f32x4 __attribute__((ext_vector_type(4)));

// ---------------- kernel 1: prep ----------------
// Blocks 0..415: qkv -> Qf32 [bh][ij][16], Qfrag/Kfrag (f16 MFMA fragments,
//   m-contraction zero-padded to 32: lanes 32..63 zero), Vfrag (25 chunks of 32
//   keys, chunk 24 keys 784..799 zeroed).
// Block 416: embedding tables Etr/Etc [m][110].
// Block 417: Wfrag = w_out as f16 A-fragments (4 ob x 4 c x 64 x 8).
__global__ __launch_bounds__(256) void prep_kernel(
    const float* __restrict__ x,
    const float* __restrict__ wq, const float* __restrict__ bq,
    const float* __restrict__ wk, const float* __restrict__ bk,
    const float* __restrict__ wv, const float* __restrict__ bv,
    const float* __restrict__ w_out,
    const float* __restrict__ rw1, const float* __restrict__ rb1,
    const float* __restrict__ rga, const float* __restrict__ rbe,
    const float* __restrict__ rw2, const float* __restrict__ rb2,
    const float* __restrict__ cw1, const float* __restrict__ cb1,
    const float* __restrict__ cga, const float* __restrict__ cbe,
    const float* __restrict__ cw2, const float* __restrict__ cb2,
    float* __restrict__ Qf32, _Float16* __restrict__ Qfrag,
    _Float16* __restrict__ Kfrag, _Float16* __restrict__ Vfrag,
    _Float16* __restrict__ Wfrag,
    float* __restrict__ Etr, float* __restrict__ Etc)
{
    const int t = threadIdx.x;
    if (blockIdx.x == 416) {                         // ---- embed path ----
        int d = -1;
        const float *w1 = rw1, *b1 = rb1, *ga = rga, *be = rbe, *w2 = rw2, *b2 = rb2;
        float* E = Etr;
        if (t < 110) { d = t; }
        else if (t >= 128 && t < 238) { d = t - 128; w1 = cw1; b1 = cb1; ga = cga; be = cbe; w2 = cw2; b2 = cb2; E = Etc; }
        if (d < 0) return;
        float u = (d < 55) ? (-1.0f + (float)d * (2.0f / 54.0f))
                           : -(-1.0f + (float)(d - 55) * (2.0f / 54.0f));
        float hb[16], mu = 0.0f;
#pragma unroll
        for (int c = 0; c < 16; ++c) { hb[c] = u * w1[c] + b1[c]; mu += hb[c]; }
        mu *= (1.0f / 16.0f);
        float var = 0.0f;
#pragma unroll
        for (int c = 0; c < 16; ++c) { float dv = hb[c] - mu; var += dv * dv; }
        var *= (1.0f / 16.0f);
        float rstd = rsqrtf(var + 1e-5f);
#pragma unroll
        for (int c = 0; c < 16; ++c) {
            float hn = ga[c] * (hb[c] - mu) * rstd + be[c];
            hb[c] = hn / (1.0f + __expf(-hn));
        }
#pragma unroll
        for (int m = 0; m < 8; ++m) {
            float e = b2[m];
#pragma unroll
            for (int c = 0; c < 16; ++c) e += hb[c] * w2[m * 16 + c];
            E[m * 110 + d] = e;
        }
        return;
    }
    if (blockIdx.x == 417) {                         // ---- Wfrag build ----
        for (int idx = t; idx < 8192; idx += 256) {
            int obc = idx >> 9, lane = (idx >> 3) & 63, j = idx & 7;
            int o  = (obc >> 2) * 16 + (lane & 15);
            int mh = (obc & 3) * 32 + (lane >> 4) * 8 + j;
            Wfrag[idx] = (_Float16)w_out[o * 128 + mh];
        }
        return;
    }

    // ---- qkv path: blocks 0..415 = (b, ij-tile of 64, h) ----
    const int bid  = blockIdx.x;
    const int b    = bid / 104, rem = bid - b * 104;
    const int tile = rem >> 3, h = rem & 7;
    const int lane = t & 63, mg = t >> 6;            // wave = m-group {4mg..4mg+3}
    const int bh   = b * 8 + h;

    // zero-fill pads (all 256 threads, BEFORE the ij guard)
    {
        int which = t >> 7, sub = (t >> 5) & 3, l32 = 32 + (t & 31);
        int qz = tile * 4 + sub;
        if (qz < 49) {
            _Float16* dst = (which ? Kfrag : Qfrag) + ((size_t)(bh * 49 + qz) * 64 + l32) * 8;
            *(f16x8*)dst = (f16x8){};
        }
        if (tile == 12 && t < 32)                    // Vfrag pad keys 784..799
            *(f16x8*)(Vfrag + ((size_t)(bh * 25 + 24) * 64 + 32 + t) * 8) = (f16x8){};
    }

    const int ij = tile * 64 + lane;
    if (ij >= NPOS) return;

    float x0 = x[(b * 3 + 0) * NPOS + ij];
    float x1 = x[(b * 3 + 1) * NPOS + ij];
    float x2 = x[(b * 3 + 2) * NPOS + ij];

    float4 qv, kv;
    float vv[4];
#pragma unroll
    for (int j = 0; j < 4; ++j) {
        int m = mg * 4 + j, oc = m * 8 + h;          // wave-uniform weight loads
        float w0, w1, w2v;
        w0 = wq[oc*3+0]; w1 = wq[oc*3+1]; w2v = wq[oc*3+2];
        ((float*)&qv)[j] = bq[oc] + w0*x0 + w1*x1 + w2v*x2;
        w0 = wk[oc*3+0]; w1 = wk[oc*3+1]; w2v = wk[oc*3+2];
        ((float*)&kv)[j] = bk[oc] + w0*x0 + w1*x1 + w2v*x2;
        w0 = wv[oc*3+0]; w1 = wv[oc*3+1]; w2v = wv[oc*3+2];
        vv[j] = bv[oc] + w0*x0 + w1*x1 + w2v*x2;
    }
    // Qf32 (rot-table build source)
    *(float4*)(Qf32 + ((size_t)(bh * NPOS + ij)) * 16 + mg * 4) = qv;
    // Qfrag/Kfrag: element [bh][ij>>4][lane'][m&7] = value(q=ij, m), lane' = (m>>3)<<4 | (ij&15)
    {
        int qt = ij >> 4;
        int lp = ((mg >> 1) << 4) | (ij & 15);
        int jb = (mg & 1) * 4;
        f16x4 q4 = {(_Float16)qv.x, (_Float16)qv.y, (_Float16)qv.z, (_Float16)qv.w};
        f16x4 k4 = {(_Float16)kv.x, (_Float16)kv.y, (_Float16)kv.z, (_Float16)kv.w};
        *(f16x4*)(Qfrag + ((size_t)(bh * 49 + qt) * 64 + lp) * 8 + jb) = q4;
        *(f16x4*)(Kfrag + ((size_t)(bh * 49 + qt) * 64 + lp) * 8 + jb) = k4;
    }
    // Vfrag: element [bh][ij>>5][((kk>>3)<<4)|m][kk&7] = V(k=ij, m)
    {
        int s5 = ij >> 5, kk = ij & 31;
        _Float16* vb = Vfrag + (((size_t)(bh * 25 + s5) * 64 + ((kk >> 3) << 4)) << 3) + (kk & 7);
#pragma unroll
        for (int j = 0; j < 4; ++j) vb[(mg * 4 + j) * 8] = (_Float16)vv[j];
    }
}

// ---------------- kernel 2: attention, 16 queries/wave, all-MFMA ----------------
// Grid = 196 blocks (b, qtile of 16), 512 thr, wave = head.
// r6 fix vs r5: rot tables normalized by the ACTUAL per-query max of the table
// values (r4-proven semantics), not the analytic bound sum|q|max|E| -- the bound
// was loose by e^6..e^17, pushing the f16 PV A-tile into subnormals/zero while
// the f32 denominator stayed exact (absmax 2.65). Plus p scaled by 2^6 (exact,
// cancels in softmax) to lift tails out of f16 subnormals.
// LDS: [0,56320) rot tables (8 waves x 16 q x 55 x f16x4);
//      [56320, +41472) union{ ebuf (1760 f32) | ptile (8 x 4 x 16 x 40h) | ovh (4g x 16q x 136h) }
__global__ __launch_bounds__(512, 1) void attn_kernel(
    const float* __restrict__ Qf32, const _Float16* __restrict__ Qfrag,
    const _Float16* __restrict__ Kfrag, const _Float16* __restrict__ Vfrag,
    const _Float16* __restrict__ Wfrag,
    const float* __restrict__ Etr, const float* __restrict__ Etc,
    const float* __restrict__ b_out, float* __restrict__ out)
{
    __shared__ __align__(16) unsigned char smem[56320 + 41472];
    const int t = threadIdx.x, wave = t >> 6, lane = t & 63;
    const int q15 = lane & 15, rg = lane >> 4;

    // bijective chunked XCD swizzle (196 = 4*25 + 4*24)
    int bid = blockIdx.x;
    int xcd = bid & 7;
    int lb  = ((xcd < 4) ? xcd * 25 : 100 + (xcd - 4) * 24) + (bid >> 3);
    const int b = lb / 49, qt = lb - b * 49;
    const int bh = b * 8 + wave;
    const int q_ij = qt * 16 + q15;                   // this lane's query (also its S-col)
    const int iq = q_ij / WDIM, jq = q_ij % WDIM;
    const float scale = 0.57735026918962576f;         // 1/sqrt(CIN=3)

    // stage Etr/Etc into LDS
    float* ebuf = (float*)(smem + 56320);
    for (int i = t; i < 1760; i += 512) ebuf[i] = (i < 880) ? Etr[i] : Etc[i - 880];
    __syncthreads();

    // ---- rot tables: exp'ed (ar,ac,ar5,ac5) per (q, delta), max-normalized ----
    {
        const float* qrow = Qf32 + ((size_t)bh * NPOS + q_ij) * 16;
        float4 a0 = ((const float4*)qrow)[0], a1 = ((const float4*)qrow)[1];
        float4 a2 = ((const float4*)qrow)[2], a3 = ((const float4*)qrow)[3];
        float ql[8] = {a0.x,a0.y,a0.z,a0.w,a1.x,a1.y,a1.z,a1.w};
        float qh[8] = {a2.x,a2.y,a2.z,a2.w,a3.x,a3.y,a3.z,a3.w};
        float var_[14], vac_[14], vr5_[14], vc5_[14];
        float mr = -3.0e38f, mc = -3.0e38f, m5r = -3.0e38f, m5c = -3.0e38f;
#pragma unroll
        for (int tv = 0; tv < 14; ++tv) {
            int dd = rg * 14 + tv;
            float ar = -3.0e38f, ac = -3.0e38f, ar5 = -3.0e38f, ac5 = -3.0e38f;
            if (dd < 55) {
                ar = 0.0f; ac = 0.0f; ar5 = 0.0f; ac5 = 0.0f;
#pragma unroll
                for (int mm = 0; mm < 8; ++mm) {
                    float qlm = ql[mm], qhm = qh[mm];
                    ar  += qlm * ebuf[mm * 110 + dd];
                    ar5 += qlm * ebuf[mm * 110 + dd + 55];
                    ac  += qhm * ebuf[880 + mm * 110 + dd];
                    ac5 += qhm * ebuf[880 + mm * 110 + dd + 55];
                }
            }
            var_[tv] = ar; vac_[tv] = ac; vr5_[tv] = ar5; vc5_[tv] = ac5;
            mr  = fmaxf(mr, ar);  mc  = fmaxf(mc, ac);
            m5r = fmaxf(m5r, ar5); m5c = fmaxf(m5c, ac5);
        }
        // per-q max across the 4 rg lanes (xor 16/32 keeps q15 fixed)
        mr  = fmaxf(mr,  __shfl_xor(mr, 16, 64));  mr  = fmaxf(mr,  __shfl_xor(mr, 32, 64));
        mc  = fmaxf(mc,  __shfl_xor(mc, 16, 64));  mc  = fmaxf(mc,  __shfl_xor(mc, 32, 64));
        m5r = fmaxf(m5r, __shfl_xor(m5r, 16, 64)); m5r = fmaxf(m5r, __shfl_xor(m5r, 32, 64));
        m5c = fmaxf(m5c, __shfl_xor(m5c, 16, 64)); m5c = fmaxf(m5c, __shfl_xor(m5c, 32, 64));
        uint2* tab = (uint2*)smem + (wave * 16 + q15) * 55;
#pragma unroll
        for (int tv = 0; tv < 14; ++tv) {
            int dd = rg * 14 + tv;
            if (dd < 55) {
                __half2 h01 = __floats2half2_rn(__expf(scale * (var_[tv] - mr)),
                                                __expf(scale * (vac_[tv] - mc)));
                __half2 h23 = __floats2half2_rn(__expf(scale * (vr5_[tv] - m5r)),
                                                __expf(scale * (vc5_[tv] - m5c)));
                uint2 w; w.x = *(unsigned int*)&h01; w.y = *(unsigned int*)&h23;
                tab[dd] = w;
            }
        }
    }
    __syncthreads();                                  // ebuf dead; ptile region usable

    // ---- Q fragment + K base ----
    f16x8 qf = *(const f16x8*)(Qfrag + ((size_t)(bh * 49 + qt) * 64 + lane) * 8);
    const _Float16* kbase = Kfrag + (size_t)bh * 49 * 64 * 8;

    // ---- pass 1: exact per-query max of raw QK dots ----
    float mx = -3.0e38f;
    for (int ch = 0; ch < 49; ++ch) {
        f16x8 kf = *(const f16x8*)(kbase + (ch * 64 + lane) * 8);
        f32x4 s = __builtin_amdgcn_mfma_f32_16x16x32_f16(kf, qf, (f32x4){0,0,0,0}, 0, 0, 0);
        mx = fmaxf(mx, fmaxf(fmaxf(s[0], s[1]), fmaxf(s[2], s[3])));
    }
    mx = fmaxf(mx, __shfl_xor(mx, 16, 64));
    mx = fmaxf(mx, __shfl_xor(mx, 32, 64));

    // ---- pass 2: S -> p (x64, f16 into 4 PV A-tiles) -> PV MFMA ----
    float ps0 = 0, ps1 = 0, ps2 = 0, ps3 = 0;
    f32x4 d0 = {0,0,0,0}, d1 = {0,0,0,0}, d2 = {0,0,0,0}, d3 = {0,0,0,0};
    _Float16* ptw = (_Float16*)(smem + 56320) + (size_t)wave * 2592;  // 4 tiles x 648 halves
    const uint2* tab = (const uint2*)smem + (wave * 16 + q15) * 55;
    const int prow  = (q15 & 3) * 4;                  // my q's PV-A row base (its tile)
    const int tbase = (q15 >> 2) * 648;               // my q's PV-A tile offset (halves)
    const f16x8* vbase = (const f16x8*)(Vfrag + (size_t)bh * 25 * 64 * 8);

    for (int pv = 0; pv < 25; ++pv) {
#pragma unroll
        for (int c2 = 0; c2 < 2; ++c2) {
            int ch = pv * 2 + c2;
            float pg[4][4];
            if (ch < 49) {
                f16x8 kf = *(const f16x8*)(kbase + (ch * 64 + lane) * 8);
                f32x4 s = __builtin_amdgcn_mfma_f32_16x16x32_f16(kf, qf, (f32x4){0,0,0,0}, 0, 0, 0);
#pragma unroll
                for (int reg = 0; reg < 4; ++reg) {
                    float ec = __expf((s[reg] - mx) * scale) * 64.0f;  // 2^6: exact, cancels
                    int k = ch * 16 + rg * 4 + reg;   // D row = key
                    int rk = (k * 2341) >> 16;        // k/28, exact for k<784
                    int ck = k - rk * WDIM;
                    uint2 tr = tab[rk - iq + 27];
                    uint2 tc = tab[ck - jq + 27];
                    float2 r01 = __half22float2(*(__half2*)&tr.x);
                    float2 r23 = __half22float2(*(__half2*)&tr.y);
                    float2 c01 = __half22float2(*(__half2*)&tc.x);
                    float2 c23 = __half22float2(*(__half2*)&tc.y);
                    pg[0][reg] = ec * r01.x * c01.y;  // g-mapping carried from r4 (verified)
                    pg[1][reg] = ec * r01.y * c23.x;
                    pg[2][reg] = ec * r23.x * c23.y;
                    pg[3][reg] = ec * r23.y * c01.x;
                    ps0 += pg[0][reg]; ps1 += pg[1][reg];
                    ps2 += pg[2][reg]; ps3 += pg[3][reg];
                }
            } else {
#pragma unroll
                for (int g = 0; g < 4; ++g)
#pragma unroll
                    for (int reg = 0; reg < 4; ++reg) pg[g][reg] = 0.0f;
            }
            int cb = rg * 4 + c2 * 16;                // 4 consecutive key-cols
#pragma unroll
            for (int g = 0; g < 4; ++g) {
                __half2 a01 = __floats2half2_rn(pg[g][0], pg[g][1]);
                __half2 a23 = __floats2half2_rn(pg[g][2], pg[g][3]);
                uint2 w; w.x = *(unsigned int*)&a01; w.y = *(unsigned int*)&a23;
                *(uint2*)(ptw + tbase + (prow + g) * 40 + cb) = w;
            }
        }
        // PV: 4 tiles x one 16x16x32 MFMA, shared V B-fragment
        f16x8 bf = vbase[pv * 64 + lane];
        f16x8 aA = *(const f16x8*)(ptw + 0 * 648 + q15 * 40 + rg * 8);
        d0 = __builtin_amdgcn_mfma_f32_16x16x32_f16(aA, bf, d0, 0, 0, 0);
        f16x8 aB = *(const f16x8*)(ptw + 1 * 648 + q15 * 40 + rg * 8);
        d1 = __builtin_amdgcn_mfma_f32_16x16x32_f16(aB, bf, d1, 0, 0, 0);
        f16x8 aC = *(const f16x8*)(ptw + 2 * 648 + q15 * 40 + rg * 8);
        d2 = __builtin_amdgcn_mfma_f32_16x16x32_f16(aC, bf, d2, 0, 0, 0);
        f16x8 aD = *(const f16x8*)(ptw + 3 * 648 + q15 * 40 + rg * 8);
        d3 = __builtin_amdgcn_mfma_f32_16x16x32_f16(aD, bf, d3, 0, 0, 0);
    }
    // full ps per q on every lane (sum the 4 key row-groups)
    ps0 += __shfl_xor(ps0, 16, 64); ps0 += __shfl_xor(ps0, 32, 64);
    ps1 += __shfl_xor(ps1, 16, 64); ps1 += __shfl_xor(ps1, 32, 64);
    ps2 += __shfl_xor(ps2, 16, 64); ps2 += __shfl_xor(ps2, 32, 64);
    ps3 += __shfl_xor(ps3, 16, 64); ps3 += __shfl_xor(ps3, 32, 64);
    float i0 = 1.0f / ps0, i1 = 1.0f / ps1, i2 = 1.0f / ps2, i3 = 1.0f / ps3;

    __syncthreads();                                  // all waves done with ptile
    // ---- epilogue: normalized out_v -> ovh[g][q][m*8+h] (f16, B-fragment layout) ----
    _Float16* ovh = (_Float16*)(smem + 56320);
    {
        int mo = q15 * 8 + wave;                      // m = q15 (D col), h = wave
        int sq;
        sq = rg;                                      // tile 0: q = 0..3
        ovh[(0*16 + sq)*136 + mo] = (_Float16)(d0[0] * __shfl(i0, sq, 64));
        ovh[(1*16 + sq)*136 + mo] = (_Float16)(d0[1] * __shfl(i1, sq, 64));
        ovh[(2*16 + sq)*136 + mo] = (_Float16)(d0[2] * __shfl(i2, sq, 64));
        ovh[(3*16 + sq)*136 + mo] = (_Float16)(d0[3] * __shfl(i3, sq, 64));
        sq = 4 + rg;
        ovh[(0*16 + sq)*136 + mo] = (_Float16)(d1[0] * __shfl(i0, sq, 64));
        ovh[(1*16 + sq)*136 + mo] = (_Float16)(d1[1] * __shfl(i1, sq, 64));
        ovh[(2*16 + sq)*136 + mo] = (_Float16)(d1[2] * __shfl(i2, sq, 64));
        ovh[(3*16 + sq)*136 + mo] = (_Float16)(d1[3] * __shfl(i3, sq, 64));
        sq = 8 + rg;
        ovh[(0*16 + sq)*136 + mo] = (_Float16)(d2[0] * __shfl(i0, sq, 64));
        ovh[(1*16 + sq)*136 + mo] = (_Float16)(d2[1] * __shfl(i1, sq, 64));
        ovh[(2*16 + sq)*136 + mo] = (_Float16)(d2[2] * __shfl(i2, sq, 64));
        ovh[(3*16 + sq)*136 + mo] = (_Float16)(d2[3] * __shfl(i3, sq, 64));
        sq = 12 + rg;
        ovh[(0*16 + sq)*136 + mo] = (_Float16)(d3[0] * __shfl(i0, sq, 64));
        ovh[(1*16 + sq)*136 + mo] = (_Float16)(d3[1] * __shfl(i1, sq, 64));
        ovh[(2*16 + sq)*136 + mo] = (_Float16)(d3[2] * __shfl(i2, sq, 64));
        ovh[(3*16 + sq)*136 + mo] = (_Float16)(d3[3] * __shfl(i3, sq, 64));
    }
    __syncthreads();

    // ---- output projection via MFMA: wave handles 2 (ob,g) tiles ----
#pragma unroll
    for (int tt2 = 0; tt2 < 2; ++tt2) {
        int tl = wave * 2 + tt2;
        int ob = tl >> 2, g = tl & 3;
        f32x4 dd = {0,0,0,0};
#pragma unroll
        for (int c = 0; c < 4; ++c) {
            f16x8 wa = *(const f16x8*)(Wfrag + ((size_t)((ob * 4 + c) * 64 + lane)) * 8);
            f16x8 vb = *(const f16x8*)(ovh + (g * 16 + q15) * 136 + c * 32 + rg * 8);
            dd = __builtin_amdgcn_mfma_f32_16x16x32_f16(wa, vb, dd, 0, 0, 0);
        }
#pragma unroll
        for (int reg = 0; reg < 4; ++reg) {
            int o = ob * 16 + rg * 4 + reg;           // D row
            out[((size_t)(b * 64 + o) * 4 + g) * NPOS + qt * 16 + q15] = dd[reg] + b_out[o];
        }
    }
}

extern "C" void kernel_launch(void* const* d_in, const int* in_sizes, int n_in,
                              void* d_out, int out_size, void* d_ws, size_t ws_size,
                              hipStream_t stream)
{
    const float* x     = (const float*)d_in[0];
    const float* wq    = (const float*)d_in[1];
    const float* bq    = (const float*)d_in[2];
    const float* wk    = (const float*)d_in[3];
    const float* bk    = (const float*)d_in[4];
    const float* wv    = (const float*)d_in[5];
    const float* bv    = (const float*)d_in[6];
    const float* w_out = (const float*)d_in[7];
    const float* b_out = (const float*)d_in[8];
    const float* rw1 = (const float*)d_in[9];
    const float* rb1 = (const float*)d_in[10];
    const float* rga = (const float*)d_in[11];
    const float* rbe = (const float*)d_in[12];
    const float* rw2 = (const float*)d_in[13];
    const float* rb2 = (const float*)d_in[14];
    const float* cw1 = (const float*)d_in[15];
    const float* cb1 = (const float*)d_in[16];
    const float* cga = (const float*)d_in[17];
    const float* cbe = (const float*)d_in[18];
    const float* cw2 = (const float*)d_in[19];
    const float* cb2 = (const float*)d_in[20];
    // d_in[21]/d_in[22] (ridx/cidx) unused: closed-form rotation indices.

    float* Qf32      = (float*)d_ws;                  // 401408 f32
    float* Etr       = Qf32 + 401408;                 // 880
    float* Etc       = Etr + 880;                     // 880
    _Float16* Qfrag  = (_Float16*)(Etc + 880);        // 32*49*64*8 = 802816 halves
    _Float16* Kfrag  = Qfrag + 802816;                // 802816
    _Float16* Vfrag  = Kfrag + 802816;                // 32*25*64*8 = 409600
    _Float16* Wfrag  = Vfrag + 409600;                // 8192

    prep_kernel<<<418, 256, 0, stream>>>(x, wq, bq, wk, bk, wv, bv, w_out,
                                         rw1, rb1, rga, rbe, rw2, rb2,
                                         cw1, cb1, cga, cbe, cw2, cb2,
                                         Qf32, Qfrag, Kfrag, Vfrag, Wfrag,
                                         Etr, Etc);
    attn_kernel<<<196, 512, 0, stream>>>(Qf32, Qfrag, Kfrag, Vfrag, Wfrag,
                                         Etr, Etc, b_out, (float*)d_out);
}

// Round 7
// 174.385 us; speedup vs baseline: 1.5445x; 1.0913x over previous
//
#include <hip/hip_runtime.h>
#include <hip/hip_fp16.h>

#define NPOS 784
#define WDIM 28

typedef _Float16 f16x8 __attribute__((ext_vector_type(8)));
typedef _Float16 f16x4 __attribute__((ext_vector_type(4)));
typedef float    f32x4 __attribute__((ext_vector_type(4)));

// ---------------- kernel 1: prep ----------------
// Blocks 0..415: qkv -> Qf32 [bh][ij][16], Qfrag/Kfrag (f16 MFMA fragments,
//   m-contraction zero-padded to 32: lanes 32..63 zero), Vfrag (25 chunks of 32
//   keys, chunk 24 keys 784..799 zeroed).
// Block 416: embedding tables Etr/Etc [m][110].
// Block 417: Wfrag = w_out as f16 A-fragments (4 ob x 4 c x 64 x 8).
__global__ __launch_bounds__(256) void prep_kernel(
    const float* __restrict__ x,
    const float* __restrict__ wq, const float* __restrict__ bq,
    const float* __restrict__ wk, const float* __restrict__ bk,
    const float* __restrict__ wv, const float* __restrict__ bv,
    const float* __restrict__ w_out,
    const float* __restrict__ rw1, const float* __restrict__ rb1,
    const float* __restrict__ rga, const float* __restrict__ rbe,
    const float* __restrict__ rw2, const float* __restrict__ rb2,
    const float* __restrict__ cw1, const float* __restrict__ cb1,
    const float* __restrict__ cga, const float* __restrict__ cbe,
    const float* __restrict__ cw2, const float* __restrict__ cb2,
    float* __restrict__ Qf32, _Float16* __restrict__ Qfrag,
    _Float16* __restrict__ Kfrag, _Float16* __restrict__ Vfrag,
    _Float16* __restrict__ Wfrag,
    float* __restrict__ Etr, float* __restrict__ Etc)
{
    const int t = threadIdx.x;
    if (blockIdx.x == 416) {                         // ---- embed path ----
        int d = -1;
        const float *w1 = rw1, *b1 = rb1, *ga = rga, *be = rbe, *w2 = rw2, *b2 = rb2;
        float* E = Etr;
        if (t < 110) { d = t; }
        else if (t >= 128 && t < 238) { d = t - 128; w1 = cw1; b1 = cb1; ga = cga; be = cbe; w2 = cw2; b2 = cb2; E = Etc; }
        if (d < 0) return;
        float u = (d < 55) ? (-1.0f + (float)d * (2.0f / 54.0f))
                           : -(-1.0f + (float)(d - 55) * (2.0f / 54.0f));
        float hb[16], mu = 0.0f;
#pragma unroll
        for (int c = 0; c < 16; ++c) { hb[c] = u * w1[c] + b1[c]; mu += hb[c]; }
        mu *= (1.0f / 16.0f);
        float var = 0.0f;
#pragma unroll
        for (int c = 0; c < 16; ++c) { float dv = hb[c] - mu; var += dv * dv; }
        var *= (1.0f / 16.0f);
        float rstd = rsqrtf(var + 1e-5f);
#pragma unroll
        for (int c = 0; c < 16; ++c) {
            float hn = ga[c] * (hb[c] - mu) * rstd + be[c];
            hb[c] = hn / (1.0f + __expf(-hn));
        }
#pragma unroll
        for (int m = 0; m < 8; ++m) {
            float e = b2[m];
#pragma unroll
            for (int c = 0; c < 16; ++c) e += hb[c] * w2[m * 16 + c];
            E[m * 110 + d] = e;
        }
        return;
    }
    if (blockIdx.x == 417) {                         // ---- Wfrag build ----
        for (int idx = t; idx < 8192; idx += 256) {
            int obc = idx >> 9, lane = (idx >> 3) & 63, j = idx & 7;
            int o  = (obc >> 2) * 16 + (lane & 15);
            int mh = (obc & 3) * 32 + (lane >> 4) * 8 + j;
            Wfrag[idx] = (_Float16)w_out[o * 128 + mh];
        }
        return;
    }

    // ---- qkv path: blocks 0..415 = (b, ij-tile of 64, h) ----
    const int bid  = blockIdx.x;
    const int b    = bid / 104, rem = bid - b * 104;
    const int tile = rem >> 3, h = rem & 7;
    const int lane = t & 63, mg = t >> 6;            // wave = m-group {4mg..4mg+3}
    const int bh   = b * 8 + h;

    // zero-fill pads (all 256 threads, BEFORE the ij guard)
    {
        int which = t >> 7, sub = (t >> 5) & 3, l32 = 32 + (t & 31);
        int qz = tile * 4 + sub;
        if (qz < 49) {
            _Float16* dst = (which ? Kfrag : Qfrag) + ((size_t)(bh * 49 + qz) * 64 + l32) * 8;
            *(f16x8*)dst = (f16x8){};
        }
        if (tile == 12 && t < 32)                    // Vfrag pad keys 784..799
            *(f16x8*)(Vfrag + ((size_t)(bh * 25 + 24) * 64 + 32 + t) * 8) = (f16x8){};
    }

    const int ij = tile * 64 + lane;
    if (ij >= NPOS) return;

    float x0 = x[(b * 3 + 0) * NPOS + ij];
    float x1 = x[(b * 3 + 1) * NPOS + ij];
    float x2 = x[(b * 3 + 2) * NPOS + ij];

    float4 qv, kv;
    float vv[4];
#pragma unroll
    for (int j = 0; j < 4; ++j) {
        int m = mg * 4 + j, oc = m * 8 + h;          // wave-uniform weight loads
        float w0, w1, w2v;
        w0 = wq[oc*3+0]; w1 = wq[oc*3+1]; w2v = wq[oc*3+2];
        ((float*)&qv)[j] = bq[oc] + w0*x0 + w1*x1 + w2v*x2;
        w0 = wk[oc*3+0]; w1 = wk[oc*3+1]; w2v = wk[oc*3+2];
        ((float*)&kv)[j] = bk[oc] + w0*x0 + w1*x1 + w2v*x2;
        w0 = wv[oc*3+0]; w1 = wv[oc*3+1]; w2v = wv[oc*3+2];
        vv[j] = bv[oc] + w0*x0 + w1*x1 + w2v*x2;
    }
    // Qf32 (rotk input)
    *(float4*)(Qf32 + ((size_t)(bh * NPOS + ij)) * 16 + mg * 4) = qv;
    // Qfrag/Kfrag: element [bh][ij>>4][lane'][m&7] = value(q=ij, m), lane' = (m>>3)<<4 | (ij&15)
    {
        int qt = ij >> 4;
        int lp = ((mg >> 1) << 4) | (ij & 15);
        int jb = (mg & 1) * 4;
        f16x4 q4 = {(_Float16)qv.x, (_Float16)qv.y, (_Float16)qv.z, (_Float16)qv.w};
        f16x4 k4 = {(_Float16)kv.x, (_Float16)kv.y, (_Float16)kv.z, (_Float16)kv.w};
        *(f16x4*)(Qfrag + ((size_t)(bh * 49 + qt) * 64 + lp) * 8 + jb) = q4;
        *(f16x4*)(Kfrag + ((size_t)(bh * 49 + qt) * 64 + lp) * 8 + jb) = k4;
    }
    // Vfrag: element [bh][ij>>5][((kk>>3)<<4)|m][kk&7] = V(k=ij, m)
    {
        int s5 = ij >> 5, kk = ij & 31;
        _Float16* vb = Vfrag + (((size_t)(bh * 25 + s5) * 64 + ((kk >> 3) << 4)) << 3) + (kk & 7);
#pragma unroll
        for (int j = 0; j < 4; ++j) vb[(mg * 4 + j) * 8] = (_Float16)vv[j];
    }
}

// ---------------- kernel 2: rot tables -> global (f16x4 per (bh,q,delta)) ----------------
// Grid = 98 blocks x 256: thread = (bh, q). Computes the 4 exp'ed rotation
// components per delta, normalized by the per-(q,component) max (r6-proven
// semantics). Recompute-twice -> no per-thread arrays -> no spill.
__global__ __launch_bounds__(256) void rotk_kernel(
    const float* __restrict__ Qf32,
    const float* __restrict__ Etr, const float* __restrict__ Etc,
    uint2* __restrict__ Tab)
{
    __shared__ float ebuf[1760];
    const int t = threadIdx.x;
    for (int i = t; i < 1760; i += 256) ebuf[i] = (i < 880) ? Etr[i] : Etc[i - 880];
    __syncthreads();

    const int idx = blockIdx.x * 256 + t;            // 25088 = 32 bh x 784 q
    const int bh = idx / NPOS, q = idx - bh * NPOS;
    const float* qrow = Qf32 + ((size_t)bh * NPOS + q) * 16;
    float4 a0 = ((const float4*)qrow)[0], a1 = ((const float4*)qrow)[1];
    float4 a2 = ((const float4*)qrow)[2], a3 = ((const float4*)qrow)[3];
    float ql[8] = {a0.x,a0.y,a0.z,a0.w,a1.x,a1.y,a1.z,a1.w};
    float qh[8] = {a2.x,a2.y,a2.z,a2.w,a3.x,a3.y,a3.z,a3.w};
    const float scale = 0.57735026918962576f;

    float mr = -3.0e38f, mc = -3.0e38f, m5r = -3.0e38f, m5c = -3.0e38f;
    for (int dd = 0; dd < 55; ++dd) {
        float ar = 0, ac = 0, ar5 = 0, ac5 = 0;
#pragma unroll
        for (int mm = 0; mm < 8; ++mm) {
            ar  += ql[mm] * ebuf[mm * 110 + dd];
            ar5 += ql[mm] * ebuf[mm * 110 + dd + 55];
            ac  += qh[mm] * ebuf[880 + mm * 110 + dd];
            ac5 += qh[mm] * ebuf[880 + mm * 110 + dd + 55];
        }
        mr  = fmaxf(mr, ar);  mc  = fmaxf(mc, ac);
        m5r = fmaxf(m5r, ar5); m5c = fmaxf(m5c, ac5);
    }
    uint2* dst = Tab + (size_t)(bh * NPOS + q) * 55;
    for (int dd = 0; dd < 55; ++dd) {
        float ar = 0, ac = 0, ar5 = 0, ac5 = 0;
#pragma unroll
        for (int mm = 0; mm < 8; ++mm) {
            ar  += ql[mm] * ebuf[mm * 110 + dd];
            ar5 += ql[mm] * ebuf[mm * 110 + dd + 55];
            ac  += qh[mm] * ebuf[880 + mm * 110 + dd];
            ac5 += qh[mm] * ebuf[880 + mm * 110 + dd + 55];
        }
        __half2 h01 = __floats2half2_rn(__expf(scale * (ar - mr)),   __expf(scale * (ac - mc)));
        __half2 h23 = __floats2half2_rn(__expf(scale * (ar5 - m5r)), __expf(scale * (ac5 - m5c)));
        uint2 w; w.x = *(unsigned int*)&h01; w.y = *(unsigned int*)&h23;
        dst[dd] = w;
    }
}

// ---------------- kernel 3: attention, 16 queries/wave, all-MFMA ----------------
// Grid = 196 blocks (b, qtile of 16), 512 thr, wave = head.
// r7 vs r6: rot-table phase moved to rotk_kernel (global Tab) -> attn just
// stages 7KB/wave coalesced (wave-private, no barrier); kills the register-fat
// table phase suspected of the 95MB spill traffic. Pass 1 unrolled; pass 2
// explicitly preloads next K/V fragments to break the load->MFMA latency chain.
// LDS: [0,56320) tab (8 waves x 16 q x 55 x 8B);
//      [56320, +41472) union{ ptile (8 x 4 x 648 h) | ovh (4g x 16q x 136 h) }
__global__ __launch_bounds__(512, 1) void attn_kernel(
    const _Float16* __restrict__ Qfrag,
    const _Float16* __restrict__ Kfrag, const _Float16* __restrict__ Vfrag,
    const _Float16* __restrict__ Wfrag,
    const uint2* __restrict__ Tab,
    const float* __restrict__ b_out, float* __restrict__ out)
{
    __shared__ __align__(16) unsigned char smem[56320 + 41472];
    const int t = threadIdx.x, wave = t >> 6, lane = t & 63;
    const int q15 = lane & 15, rg = lane >> 4;

    // bijective chunked XCD swizzle (196 = 4*25 + 4*24)
    int bid = blockIdx.x;
    int xcd = bid & 7;
    int lb  = ((xcd < 4) ? xcd * 25 : 100 + (xcd - 4) * 24) + (bid >> 3);
    const int b = lb / 49, qt = lb - b * 49;
    const int bh = b * 8 + wave;
    const int q_ij = qt * 16 + q15;                   // this lane's query (its S-col)
    const int iq = q_ij / WDIM, jq = q_ij % WDIM;
    const float scale = 0.57735026918962576f;         // 1/sqrt(CIN=3)

    // ---- stage this wave's rot table: 880 uint2, coalesced, wave-private ----
    {
        const uint2* gt = Tab + (size_t)(bh * NPOS + qt * 16) * 55;
        uint2* tl = (uint2*)smem + wave * 880;
#pragma unroll
        for (int i = 0; i < 14; ++i) {
            int o = i * 64 + lane;
            if (o < 880) tl[o] = gt[o];
        }
    }

    // ---- Q fragment + K base ----
    f16x8 qf = *(const f16x8*)(Qfrag + ((size_t)(bh * 49 + qt) * 64 + lane) * 8);
    const f16x8* kchunk = (const f16x8*)(Kfrag + (size_t)bh * 49 * 64 * 8);

    // ---- pass 1: exact per-query max of raw QK dots (independent MFMAs) ----
    float mx = -3.0e38f;
#pragma unroll 7
    for (int ch = 0; ch < 49; ++ch) {
        f16x8 kf = kchunk[ch * 64 + lane];
        f32x4 s = __builtin_amdgcn_mfma_f32_16x16x32_f16(kf, qf, (f32x4){0,0,0,0}, 0, 0, 0);
        mx = fmaxf(mx, fmaxf(fmaxf(s[0], s[1]), fmaxf(s[2], s[3])));
    }
    mx = fmaxf(mx, __shfl_xor(mx, 16, 64));
    mx = fmaxf(mx, __shfl_xor(mx, 32, 64));

    // ---- pass 2: S -> p (x64, f16 into 4 PV A-tiles) -> PV MFMA, pipelined ----
    float ps0 = 0, ps1 = 0, ps2 = 0, ps3 = 0;
    f32x4 d0 = {0,0,0,0}, d1 = {0,0,0,0}, d2 = {0,0,0,0}, d3 = {0,0,0,0};
    _Float16* ptw = (_Float16*)(smem + 56320) + (size_t)wave * 2592;  // 4 tiles x 648 halves
    const uint2* tab = (const uint2*)smem + (wave * 16 + q15) * 55;
    const int prow  = (q15 & 3) * 4;                  // my q's PV-A row base (its tile)
    const int tbase = (q15 >> 2) * 648;               // my q's PV-A tile offset (halves)
    const f16x8* vbase = (const f16x8*)(Vfrag + (size_t)bh * 25 * 64 * 8);

    f16x8 kfA = kchunk[0 * 64 + lane];
    f16x8 kfB = kchunk[1 * 64 + lane];
    f16x8 bf  = vbase[lane];
    for (int pv = 0; pv < 25; ++pv) {
        // prefetch next iteration's fragments (clamped; hides load latency)
        int nA = (pv * 2 + 2 < 49) ? pv * 2 + 2 : 48;
        int nB = (pv * 2 + 3 < 49) ? pv * 2 + 3 : 48;
        int nV = (pv + 1 < 25) ? pv + 1 : 24;
        f16x8 kfA2 = kchunk[nA * 64 + lane];
        f16x8 kfB2 = kchunk[nB * 64 + lane];
        f16x8 bf2  = vbase[nV * 64 + lane];
#pragma unroll
        for (int c2 = 0; c2 < 2; ++c2) {
            int ch = pv * 2 + c2;
            float pg[4][4];
            if (ch < 49) {
                f16x8 kf = c2 ? kfB : kfA;
                f32x4 s = __builtin_amdgcn_mfma_f32_16x16x32_f16(kf, qf, (f32x4){0,0,0,0}, 0, 0, 0);
#pragma unroll
                for (int reg = 0; reg < 4; ++reg) {
                    float ec = __expf((s[reg] - mx) * scale) * 64.0f;  // 2^6: exact, cancels
                    int k = ch * 16 + rg * 4 + reg;   // D row = key
                    int rk = (k * 2341) >> 16;        // k/28, exact for k<784
                    int ck = k - rk * WDIM;
                    uint2 tr = tab[rk - iq + 27];
                    uint2 tc = tab[ck - jq + 27];
                    float2 r01 = __half22float2(*(__half2*)&tr.x);
                    float2 r23 = __half22float2(*(__half2*)&tr.y);
                    float2 c01 = __half22float2(*(__half2*)&tc.x);
                    float2 c23 = __half22float2(*(__half2*)&tc.y);
                    pg[0][reg] = ec * r01.x * c01.y;  // g-mapping carried from r4 (verified)
                    pg[1][reg] = ec * r01.y * c23.x;
                    pg[2][reg] = ec * r23.x * c23.y;
                    pg[3][reg] = ec * r23.y * c01.x;
                    ps0 += pg[0][reg]; ps1 += pg[1][reg];
                    ps2 += pg[2][reg]; ps3 += pg[3][reg];
                }
            } else {
#pragma unroll
                for (int g = 0; g < 4; ++g)
#pragma unroll
                    for (int reg = 0; reg < 4; ++reg) pg[g][reg] = 0.0f;
            }
            int cb = rg * 4 + c2 * 16;                // 4 consecutive key-cols
#pragma unroll
            for (int g = 0; g < 4; ++g) {
                __half2 a01 = __floats2half2_rn(pg[g][0], pg[g][1]);
                __half2 a23 = __floats2half2_rn(pg[g][2], pg[g][3]);
                uint2 w; w.x = *(unsigned int*)&a01; w.y = *(unsigned int*)&a23;
                *(uint2*)(ptw + tbase + (prow + g) * 40 + cb) = w;
            }
        }
        // PV: 4 tiles x one 16x16x32 MFMA, shared V B-fragment
        f16x8 aA = *(const f16x8*)(ptw + 0 * 648 + q15 * 40 + rg * 8);
        d0 = __builtin_amdgcn_mfma_f32_16x16x32_f16(aA, bf, d0, 0, 0, 0);
        f16x8 aB = *(const f16x8*)(ptw + 1 * 648 + q15 * 40 + rg * 8);
        d1 = __builtin_amdgcn_mfma_f32_16x16x32_f16(aB, bf, d1, 0, 0, 0);
        f16x8 aC = *(const f16x8*)(ptw + 2 * 648 + q15 * 40 + rg * 8);
        d2 = __builtin_amdgcn_mfma_f32_16x16x32_f16(aC, bf, d2, 0, 0, 0);
        f16x8 aD = *(const f16x8*)(ptw + 3 * 648 + q15 * 40 + rg * 8);
        d3 = __builtin_amdgcn_mfma_f32_16x16x32_f16(aD, bf, d3, 0, 0, 0);
        kfA = kfA2; kfB = kfB2; bf = bf2;
    }
    // full ps per q on every lane (sum the 4 key row-groups)
    ps0 += __shfl_xor(ps0, 16, 64); ps0 += __shfl_xor(ps0, 32, 64);
    ps1 += __shfl_xor(ps1, 16, 64); ps1 += __shfl_xor(ps1, 32, 64);
    ps2 += __shfl_xor(ps2, 16, 64); ps2 += __shfl_xor(ps2, 32, 64);
    ps3 += __shfl_xor(ps3, 16, 64); ps3 += __shfl_xor(ps3, 32, 64);
    float i0 = 1.0f / ps0, i1 = 1.0f / ps1, i2 = 1.0f / ps2, i3 = 1.0f / ps3;

    __syncthreads();                                  // all waves done with ptile
    // ---- epilogue: normalized out_v -> ovh[g][q][m*8+h] (f16, B-fragment layout) ----
    _Float16* ovh = (_Float16*)(smem + 56320);
    {
        int mo = q15 * 8 + wave;                      // m = q15 (D col), h = wave
        int sq;
        sq = rg;                                      // tile 0: q = 0..3
        ovh[(0*16 + sq)*136 + mo] = (_Float16)(d0[0] * __shfl(i0, sq, 64));
        ovh[(1*16 + sq)*136 + mo] = (_Float16)(d0[1] * __shfl(i1, sq, 64));
        ovh[(2*16 + sq)*136 + mo] = (_Float16)(d0[2] * __shfl(i2, sq, 64));
        ovh[(3*16 + sq)*136 + mo] = (_Float16)(d0[3] * __shfl(i3, sq, 64));
        sq = 4 + rg;
        ovh[(0*16 + sq)*136 + mo] = (_Float16)(d1[0] * __shfl(i0, sq, 64));
        ovh[(1*16 + sq)*136 + mo] = (_Float16)(d1[1] * __shfl(i1, sq, 64));
        ovh[(2*16 + sq)*136 + mo] = (_Float16)(d1[2] * __shfl(i2, sq, 64));
        ovh[(3*16 + sq)*136 + mo] = (_Float16)(d1[3] * __shfl(i3, sq, 64));
        sq = 8 + rg;
        ovh[(0*16 + sq)*136 + mo] = (_Float16)(d2[0] * __shfl(i0, sq, 64));
        ovh[(1*16 + sq)*136 + mo] = (_Float16)(d2[1] * __shfl(i1, sq, 64));
        ovh[(2*16 + sq)*136 + mo] = (_Float16)(d2[2] * __shfl(i2, sq, 64));
        ovh[(3*16 + sq)*136 + mo] = (_Float16)(d2[3] * __shfl(i3, sq, 64));
        sq = 12 + rg;
        ovh[(0*16 + sq)*136 + mo] = (_Float16)(d3[0] * __shfl(i0, sq, 64));
        ovh[(1*16 + sq)*136 + mo] = (_Float16)(d3[1] * __shfl(i1, sq, 64));
        ovh[(2*16 + sq)*136 + mo] = (_Float16)(d3[2] * __shfl(i2, sq, 64));
        ovh[(3*16 + sq)*136 + mo] = (_Float16)(d3[3] * __shfl(i3, sq, 64));
    }
    __syncthreads();

    // ---- output projection via MFMA: wave handles 2 (ob,g) tiles ----
#pragma unroll
    for (int tt2 = 0; tt2 < 2; ++tt2) {
        int tl = wave * 2 + tt2;
        int ob = tl >> 2, g = tl & 3;
        f32x4 dd = {0,0,0,0};
#pragma unroll
        for (int c = 0; c < 4; ++c) {
            f16x8 wa = *(const f16x8*)(Wfrag + ((size_t)((ob * 4 + c) * 64 + lane)) * 8);
            f16x8 vb = *(const f16x8*)(ovh + (g * 16 + q15) * 136 + c * 32 + rg * 8);
            dd = __builtin_amdgcn_mfma_f32_16x16x32_f16(wa, vb, dd, 0, 0, 0);
        }
#pragma unroll
        for (int reg = 0; reg < 4; ++reg) {
            int o = ob * 16 + rg * 4 + reg;           // D row
            out[((size_t)(b * 64 + o) * 4 + g) * NPOS + qt * 16 + q15] = dd[reg] + b_out[o];
        }
    }
}

extern "C" void kernel_launch(void* const* d_in, const int* in_sizes, int n_in,
                              void* d_out, int out_size, void* d_ws, size_t ws_size,
                              hipStream_t stream)
{
    const float* x     = (const float*)d_in[0];
    const float* wq    = (const float*)d_in[1];
    const float* bq    = (const float*)d_in[2];
    const float* wk    = (const float*)d_in[3];
    const float* bk    = (const float*)d_in[4];
    const float* wv    = (const float*)d_in[5];
    const float* bv    = (const float*)d_in[6];
    const float* w_out = (const float*)d_in[7];
    const float* b_out = (const float*)d_in[8];
    const float* rw1 = (const float*)d_in[9];
    const float* rb1 = (const float*)d_in[10];
    const float* rga = (const float*)d_in[11];
    const float* rbe = (const float*)d_in[12];
    const float* rw2 = (const float*)d_in[13];
    const float* rb2 = (const float*)d_in[14];
    const float* cw1 = (const float*)d_in[15];
    const float* cb1 = (const float*)d_in[16];
    const float* cga = (const float*)d_in[17];
    const float* cbe = (const float*)d_in[18];
    const float* cw2 = (const float*)d_in[19];
    const float* cb2 = (const float*)d_in[20];
    // d_in[21]/d_in[22] (ridx/cidx) unused: closed-form rotation indices.

    float* Qf32      = (float*)d_ws;                  // 401408 f32
    float* Etr       = Qf32 + 401408;                 // 880
    float* Etc       = Etr + 880;                     // 880
    _Float16* Qfrag  = (_Float16*)(Etc + 880);        // 32*49*64*8 = 802816 halves
    _Float16* Kfrag  = Qfrag + 802816;                // 802816
    _Float16* Vfrag  = Kfrag + 802816;                // 32*25*64*8 = 409600
    _Float16* Wfrag  = Vfrag + 409600;                // 8192
    uint2*    Tab    = (uint2*)(Wfrag + 8192);        // 25088*55 uint2 = 11.0 MB

    prep_kernel<<<418, 256, 0, stream>>>(x, wq, bq, wk, bk, wv, bv, w_out,
                                         rw1, rb1, rga, rbe, rw2, rb2,
                                         cw1, cb1, cga, cbe, cw2, cb2,
                                         Qf32, Qfrag, Kfrag, Vfrag, Wfrag,
                                         Etr, Etc);
    rotk_kernel<<<98, 256, 0, stream>>>(Qf32, Etr, Etc, Tab);
    attn_kernel<<<196, 512, 0, stream>>>(Qfrag, Kfrag, Vfrag, Wfrag, Tab,
                                         b_out, (float*)d_out);
}

// Round 8
// 158.803 us; speedup vs baseline: 1.6960x; 1.0981x over previous
//
#include <hip/hip_runtime.h>
#include <hip/hip_fp16.h>

#define NPOS 784
#define WDIM 28

typedef _Float16 f16x8 __attribute__((ext_vector_type(8)));
typedef _Float16 f16x4 __attribute__((ext_vector_type(4)));
typedef float    f32x4 __attribute__((ext_vector_type(4)));

// ---------------- kernel 1: prep ----------------
// Blocks 0..415: k/v -> Kfrag (f16 MFMA fragments, m-contraction zero-padded to
//   32: lanes 32..63 zero), Vfrag (25 chunks of 32 keys, keys 784..799 zeroed).
// Block 416: embedding tables Etr/Etc [m][110].
// Block 417: Wfrag = w_out as f16 A-fragments (4 ob x 4 c x 64 x 8).
// (Q is computed on the fly inside attn -- no cross-block reuse.)
__global__ __launch_bounds__(256) void prep_kernel(
    const float* __restrict__ x,
    const float* __restrict__ wk, const float* __restrict__ bk,
    const float* __restrict__ wv, const float* __restrict__ bv,
    const float* __restrict__ w_out,
    const float* __restrict__ rw1, const float* __restrict__ rb1,
    const float* __restrict__ rga, const float* __restrict__ rbe,
    const float* __restrict__ rw2, const float* __restrict__ rb2,
    const float* __restrict__ cw1, const float* __restrict__ cb1,
    const float* __restrict__ cga, const float* __restrict__ cbe,
    const float* __restrict__ cw2, const float* __restrict__ cb2,
    _Float16* __restrict__ Kfrag, _Float16* __restrict__ Vfrag,
    _Float16* __restrict__ Wfrag,
    float* __restrict__ Etr, float* __restrict__ Etc)
{
    const int t = threadIdx.x;
    if (blockIdx.x == 416) {                         // ---- embed path ----
        int d = -1;
        const float *w1 = rw1, *b1 = rb1, *ga = rga, *be = rbe, *w2 = rw2, *b2 = rb2;
        float* E = Etr;
        if (t < 110) { d = t; }
        else if (t >= 128 && t < 238) { d = t - 128; w1 = cw1; b1 = cb1; ga = cga; be = cbe; w2 = cw2; b2 = cb2; E = Etc; }
        if (d < 0) return;
        float u = (d < 55) ? (-1.0f + (float)d * (2.0f / 54.0f))
                           : -(-1.0f + (float)(d - 55) * (2.0f / 54.0f));
        float hb[16], mu = 0.0f;
#pragma unroll
        for (int c = 0; c < 16; ++c) { hb[c] = u * w1[c] + b1[c]; mu += hb[c]; }
        mu *= (1.0f / 16.0f);
        float var = 0.0f;
#pragma unroll
        for (int c = 0; c < 16; ++c) { float dv = hb[c] - mu; var += dv * dv; }
        var *= (1.0f / 16.0f);
        float rstd = rsqrtf(var + 1e-5f);
#pragma unroll
        for (int c = 0; c < 16; ++c) {
            float hn = ga[c] * (hb[c] - mu) * rstd + be[c];
            hb[c] = hn / (1.0f + __expf(-hn));
        }
#pragma unroll
        for (int m = 0; m < 8; ++m) {
            float e = b2[m];
#pragma unroll
            for (int c = 0; c < 16; ++c) e += hb[c] * w2[m * 16 + c];
            E[m * 110 + d] = e;
        }
        return;
    }
    if (blockIdx.x == 417) {                         // ---- Wfrag build ----
        for (int idx = t; idx < 8192; idx += 256) {
            int obc = idx >> 9, lane = (idx >> 3) & 63, j = idx & 7;
            int o  = (obc >> 2) * 16 + (lane & 15);
            int mh = (obc & 3) * 32 + (lane >> 4) * 8 + j;
            Wfrag[idx] = (_Float16)w_out[o * 128 + mh];
        }
        return;
    }

    // ---- k/v path: blocks 0..415 = (b, ij-tile of 64, h) ----
    const int bid  = blockIdx.x;
    const int b    = bid / 104, rem = bid - b * 104;
    const int tile = rem >> 3, h = rem & 7;
    const int lane = t & 63, mg = t >> 6;            // wave = m-group {4mg..4mg+3}
    const int bh   = b * 8 + h;

    // zero-fill pads (all 256 threads, BEFORE the ij guard)
    {
        if (t < 128) {                               // Kfrag contraction pad lanes 32..63
            int sub = (t >> 5) & 3, l32 = 32 + (t & 31);
            int qz = tile * 4 + sub;
            if (qz < 49)
                *(f16x8*)(Kfrag + ((size_t)(bh * 49 + qz) * 64 + l32) * 8) = (f16x8){};
        }
        if (tile == 12 && t < 32)                    // Vfrag pad keys 784..799
            *(f16x8*)(Vfrag + ((size_t)(bh * 25 + 24) * 64 + 32 + t) * 8) = (f16x8){};
    }

    const int ij = tile * 64 + lane;
    if (ij >= NPOS) return;

    float x0 = x[(b * 3 + 0) * NPOS + ij];
    float x1 = x[(b * 3 + 1) * NPOS + ij];
    float x2 = x[(b * 3 + 2) * NPOS + ij];

    float4 kv;
    float vv[4];
#pragma unroll
    for (int j = 0; j < 4; ++j) {
        int m = mg * 4 + j, oc = m * 8 + h;          // wave-uniform weight loads
        float w0, w1, w2v;
        w0 = wk[oc*3+0]; w1 = wk[oc*3+1]; w2v = wk[oc*3+2];
        ((float*)&kv)[j] = bk[oc] + w0*x0 + w1*x1 + w2v*x2;
        w0 = wv[oc*3+0]; w1 = wv[oc*3+1]; w2v = wv[oc*3+2];
        vv[j] = bv[oc] + w0*x0 + w1*x1 + w2v*x2;
    }
    // Kfrag: element [bh][ij>>4][lane'][m&7] = K(q=ij, m), lane' = (m>>3)<<4 | (ij&15)
    {
        int qt = ij >> 4;
        int lp = ((mg >> 1) << 4) | (ij & 15);
        int jb = (mg & 1) * 4;
        f16x4 k4 = {(_Float16)kv.x, (_Float16)kv.y, (_Float16)kv.z, (_Float16)kv.w};
        *(f16x4*)(Kfrag + ((size_t)(bh * 49 + qt) * 64 + lp) * 8 + jb) = k4;
    }
    // Vfrag: element [bh][ij>>5][((kk>>3)<<4)|m][kk&7] = V(k=ij, m)
    {
        int s5 = ij >> 5, kk = ij & 31;
        _Float16* vb = Vfrag + (((size_t)(bh * 25 + s5) * 64 + ((kk >> 3) << 4)) << 3) + (kk & 7);
#pragma unroll
        for (int j = 0; j < 4; ++j) vb[(mg * 4 + j) * 8] = (_Float16)vv[j];
    }
}

// ---------------- kernel 2: attention, 16 queries/wave, all-MFMA ----------------
// Grid = 196 blocks (b, qtile of 16), 512 thr, wave = head.
// r8 vs r7: rotk merged in (array-free recompute-twice build, rule-#20-safe:
// no runtime-indexed arrays -> no scratch) and Q computed on the fly -> Tab /
// Qf32 / Qfrag global round-trips and one kernel launch deleted.
// LDS: [0,56320) tab (8 waves x 16 q x 55 x 8B);
//      [56320, +41472) union{ ebuf 1760 f32 | ptile (8 x 4 x 648 h) | ovh (4g x 16q x 136 h) }
__global__ __launch_bounds__(512, 1) void attn_kernel(
    const _Float16* __restrict__ Kfrag, const _Float16* __restrict__ Vfrag,
    const _Float16* __restrict__ Wfrag,
    const float* __restrict__ Etr, const float* __restrict__ Etc,
    const float* __restrict__ x,
    const float* __restrict__ wq, const float* __restrict__ bq,
    const float* __restrict__ b_out, float* __restrict__ out)
{
    __shared__ __align__(16) unsigned char smem[56320 + 41472];
    const int t = threadIdx.x, wave = t >> 6, lane = t & 63;
    const int q15 = lane & 15, rg = lane >> 4;

    // bijective chunked XCD swizzle (196 = 4*25 + 4*24)
    int bid = blockIdx.x;
    int xcd = bid & 7;
    int lb  = ((xcd < 4) ? xcd * 25 : 100 + (xcd - 4) * 24) + (bid >> 3);
    const int b = lb / 49, qt = lb - b * 49;
    const int bh = b * 8 + wave;
    const int q_ij = qt * 16 + q15;                   // this lane's query (its S-col)
    const int iq = q_ij / WDIM, jq = q_ij % WDIM;
    const float scale = 0.57735026918962576f;         // 1/sqrt(CIN=3)

    // ---- stage embed tables into LDS (block-shared) ----
    float* ebuf = (float*)(smem + 56320);
    for (int i = t; i < 1760; i += 512) ebuf[i] = (i < 880) ? Etr[i] : Etc[i - 880];

    // ---- q on the fly (f32 for tables; f16 fragment for QK MFMA) ----
    float ql[8], qh[8];                               // unroll-only indexing -> regs
    {
        float x0 = x[(b * 3 + 0) * NPOS + q_ij];
        float x1 = x[(b * 3 + 1) * NPOS + q_ij];
        float x2 = x[(b * 3 + 2) * NPOS + q_ij];
#pragma unroll
        for (int m = 0; m < 8; ++m) {
            int oc = m * 8 + wave;                    // wave-uniform weights
            ql[m] = bq[oc] + wq[oc*3+0]*x0 + wq[oc*3+1]*x1 + wq[oc*3+2]*x2;
        }
#pragma unroll
        for (int m = 0; m < 8; ++m) {
            int oc = (m + 8) * 8 + wave;
            qh[m] = bq[oc] + wq[oc*3+0]*x0 + wq[oc*3+1]*x1 + wq[oc*3+2]*x2;
        }
    }
    f16x8 qf = {};                                    // B-frag: rows m, cols q; m>=16 pad
    if (rg == 0) {
#pragma unroll
        for (int j = 0; j < 8; ++j) qf[j] = (_Float16)ql[j];
    } else if (rg == 1) {
#pragma unroll
        for (int j = 0; j < 8; ++j) qf[j] = (_Float16)qh[j];
    }
    __syncthreads();                                  // ebuf ready

    // ---- rot-table build (array-free, recompute-twice; r7 rotk semantics) ----
    {
        float mr = -3.0e38f, mc = -3.0e38f, m5r = -3.0e38f, m5c = -3.0e38f;
        for (int tv = 0; tv < 14; ++tv) {
            int dd = rg * 14 + tv;
            if (dd < 55) {
                float ar = 0, ac = 0, ar5 = 0, ac5 = 0;
#pragma unroll
                for (int mm = 0; mm < 8; ++mm) {
                    ar  += ql[mm] * ebuf[mm * 110 + dd];
                    ar5 += ql[mm] * ebuf[mm * 110 + dd + 55];
                    ac  += qh[mm] * ebuf[880 + mm * 110 + dd];
                    ac5 += qh[mm] * ebuf[880 + mm * 110 + dd + 55];
                }
                mr  = fmaxf(mr, ar);  mc  = fmaxf(mc, ac);
                m5r = fmaxf(m5r, ar5); m5c = fmaxf(m5c, ac5);
            }
        }
        // per-q max across the 4 rg lanes (xor 16/32 keeps q15 fixed)
        mr  = fmaxf(mr,  __shfl_xor(mr, 16, 64));  mr  = fmaxf(mr,  __shfl_xor(mr, 32, 64));
        mc  = fmaxf(mc,  __shfl_xor(mc, 16, 64));  mc  = fmaxf(mc,  __shfl_xor(mc, 32, 64));
        m5r = fmaxf(m5r, __shfl_xor(m5r, 16, 64)); m5r = fmaxf(m5r, __shfl_xor(m5r, 32, 64));
        m5c = fmaxf(m5c, __shfl_xor(m5c, 16, 64)); m5c = fmaxf(m5c, __shfl_xor(m5c, 32, 64));
        uint2* tabw = (uint2*)smem + (wave * 16 + q15) * 55;
        for (int tv = 0; tv < 14; ++tv) {
            int dd = rg * 14 + tv;
            if (dd < 55) {
                float ar = 0, ac = 0, ar5 = 0, ac5 = 0;
#pragma unroll
                for (int mm = 0; mm < 8; ++mm) {
                    ar  += ql[mm] * ebuf[mm * 110 + dd];
                    ar5 += ql[mm] * ebuf[mm * 110 + dd + 55];
                    ac  += qh[mm] * ebuf[880 + mm * 110 + dd];
                    ac5 += qh[mm] * ebuf[880 + mm * 110 + dd + 55];
                }
                __half2 h01 = __floats2half2_rn(__expf(scale * (ar - mr)),
                                                __expf(scale * (ac - mc)));
                __half2 h23 = __floats2half2_rn(__expf(scale * (ar5 - m5r)),
                                                __expf(scale * (ac5 - m5c)));
                uint2 w; w.x = *(unsigned int*)&h01; w.y = *(unsigned int*)&h23;
                tabw[dd] = w;
            }
        }
    }
    __syncthreads();                                  // all ebuf reads done -> ptile usable

    const f16x8* kchunk = (const f16x8*)(Kfrag + (size_t)bh * 49 * 64 * 8);

    // ---- pass 1: exact per-query max of raw QK dots (independent MFMAs) ----
    float mx = -3.0e38f;
#pragma unroll 7
    for (int ch = 0; ch < 49; ++ch) {
        f16x8 kf = kchunk[ch * 64 + lane];
        f32x4 s = __builtin_amdgcn_mfma_f32_16x16x32_f16(kf, qf, (f32x4){0,0,0,0}, 0, 0, 0);
        mx = fmaxf(mx, fmaxf(fmaxf(s[0], s[1]), fmaxf(s[2], s[3])));
    }
    mx = fmaxf(mx, __shfl_xor(mx, 16, 64));
    mx = fmaxf(mx, __shfl_xor(mx, 32, 64));

    // ---- pass 2: S -> p (x64, f16 into 4 PV A-tiles) -> PV MFMA, pipelined ----
    float ps0 = 0, ps1 = 0, ps2 = 0, ps3 = 0;
    f32x4 d0 = {0,0,0,0}, d1 = {0,0,0,0}, d2 = {0,0,0,0}, d3 = {0,0,0,0};
    _Float16* ptw = (_Float16*)(smem + 56320) + (size_t)wave * 2592;  // 4 tiles x 648 halves
    const uint2* tab = (const uint2*)smem + (wave * 16 + q15) * 55;
    const int prow  = (q15 & 3) * 4;                  // my q's PV-A row base (its tile)
    const int tbase = (q15 >> 2) * 648;               // my q's PV-A tile offset (halves)
    const f16x8* vbase = (const f16x8*)(Vfrag + (size_t)bh * 25 * 64 * 8);

    f16x8 kfA = kchunk[0 * 64 + lane];
    f16x8 kfB = kchunk[1 * 64 + lane];
    f16x8 bf  = vbase[lane];
    for (int pv = 0; pv < 25; ++pv) {
        // prefetch next iteration's fragments (clamped; hides load latency)
        int nA = (pv * 2 + 2 < 49) ? pv * 2 + 2 : 48;
        int nB = (pv * 2 + 3 < 49) ? pv * 2 + 3 : 48;
        int nV = (pv + 1 < 25) ? pv + 1 : 24;
        f16x8 kfA2 = kchunk[nA * 64 + lane];
        f16x8 kfB2 = kchunk[nB * 64 + lane];
        f16x8 bf2  = vbase[nV * 64 + lane];
#pragma unroll
        for (int c2 = 0; c2 < 2; ++c2) {
            int ch = pv * 2 + c2;
            float pg[4][4];
            if (ch < 49) {
                f16x8 kf = c2 ? kfB : kfA;
                f32x4 s = __builtin_amdgcn_mfma_f32_16x16x32_f16(kf, qf, (f32x4){0,0,0,0}, 0, 0, 0);
#pragma unroll
                for (int reg = 0; reg < 4; ++reg) {
                    float ec = __expf((s[reg] - mx) * scale) * 64.0f;  // 2^6: exact, cancels
                    int k = ch * 16 + rg * 4 + reg;   // D row = key
                    int rk = (k * 2341) >> 16;        // k/28, exact for k<784
                    int ck = k - rk * WDIM;
                    uint2 tr = tab[rk - iq + 27];
                    uint2 tc = tab[ck - jq + 27];
                    float2 r01 = __half22float2(*(__half2*)&tr.x);
                    float2 r23 = __half22float2(*(__half2*)&tr.y);
                    float2 c01 = __half22float2(*(__half2*)&tc.x);
                    float2 c23 = __half22float2(*(__half2*)&tc.y);
                    pg[0][reg] = ec * r01.x * c01.y;  // g-mapping carried from r4 (verified)
                    pg[1][reg] = ec * r01.y * c23.x;
                    pg[2][reg] = ec * r23.x * c23.y;
                    pg[3][reg] = ec * r23.y * c01.x;
                    ps0 += pg[0][reg]; ps1 += pg[1][reg];
                    ps2 += pg[2][reg]; ps3 += pg[3][reg];
                }
            } else {
#pragma unroll
                for (int g = 0; g < 4; ++g)
#pragma unroll
                    for (int reg = 0; reg < 4; ++reg) pg[g][reg] = 0.0f;
            }
            int cb = rg * 4 + c2 * 16;                // 4 consecutive key-cols
#pragma unroll
            for (int g = 0; g < 4; ++g) {
                __half2 a01 = __floats2half2_rn(pg[g][0], pg[g][1]);
                __half2 a23 = __floats2half2_rn(pg[g][2], pg[g][3]);
                uint2 w; w.x = *(unsigned int*)&a01; w.y = *(unsigned int*)&a23;
                *(uint2*)(ptw + tbase + (prow + g) * 40 + cb) = w;
            }
        }
        // PV: 4 tiles x one 16x16x32 MFMA, shared V B-fragment
        f16x8 aA = *(const f16x8*)(ptw + 0 * 648 + q15 * 40 + rg * 8);
        d0 = __builtin_amdgcn_mfma_f32_16x16x32_f16(aA, bf, d0, 0, 0, 0);
        f16x8 aB = *(const f16x8*)(ptw + 1 * 648 + q15 * 40 + rg * 8);
        d1 = __builtin_amdgcn_mfma_f32_16x16x32_f16(aB, bf, d1, 0, 0, 0);
        f16x8 aC = *(const f16x8*)(ptw + 2 * 648 + q15 * 40 + rg * 8);
        d2 = __builtin_amdgcn_mfma_f32_16x16x32_f16(aC, bf, d2, 0, 0, 0);
        f16x8 aD = *(const f16x8*)(ptw + 3 * 648 + q15 * 40 + rg * 8);
        d3 = __builtin_amdgcn_mfma_f32_16x16x32_f16(aD, bf, d3, 0, 0, 0);
        kfA = kfA2; kfB = kfB2; bf = bf2;
    }
    // full ps per q on every lane (sum the 4 key row-groups)
    ps0 += __shfl_xor(ps0, 16, 64); ps0 += __shfl_xor(ps0, 32, 64);
    ps1 += __shfl_xor(ps1, 16, 64); ps1 += __shfl_xor(ps1, 32, 64);
    ps2 += __shfl_xor(ps2, 16, 64); ps2 += __shfl_xor(ps2, 32, 64);
    ps3 += __shfl_xor(ps3, 16, 64); ps3 += __shfl_xor(ps3, 32, 64);
    float i0 = 1.0f / ps0, i1 = 1.0f / ps1, i2 = 1.0f / ps2, i3 = 1.0f / ps3;

    __syncthreads();                                  // all waves done with ptile
    // ---- epilogue: normalized out_v -> ovh[g][q][m*8+h] (f16, B-fragment layout) ----
    _Float16* ovh = (_Float16*)(smem + 56320);
    {
        int mo = q15 * 8 + wave;                      // m = q15 (D col), h = wave
        int sq;
        sq = rg;                                      // tile 0: q = 0..3
        ovh[(0*16 + sq)*136 + mo] = (_Float16)(d0[0] * __shfl(i0, sq, 64));
        ovh[(1*16 + sq)*136 + mo] = (_Float16)(d0[1] * __shfl(i1, sq, 64));
        ovh[(2*16 + sq)*136 + mo] = (_Float16)(d0[2] * __shfl(i2, sq, 64));
        ovh[(3*16 + sq)*136 + mo] = (_Float16)(d0[3] * __shfl(i3, sq, 64));
        sq = 4 + rg;
        ovh[(0*16 + sq)*136 + mo] = (_Float16)(d1[0] * __shfl(i0, sq, 64));
        ovh[(1*16 + sq)*136 + mo] = (_Float16)(d1[1] * __shfl(i1, sq, 64));
        ovh[(2*16 + sq)*136 + mo] = (_Float16)(d1[2] * __shfl(i2, sq, 64));
        ovh[(3*16 + sq)*136 + mo] = (_Float16)(d1[3] * __shfl(i3, sq, 64));
        sq = 8 + rg;
        ovh[(0*16 + sq)*136 + mo] = (_Float16)(d2[0] * __shfl(i0, sq, 64));
        ovh[(1*16 + sq)*136 + mo] = (_Float16)(d2[1] * __shfl(i1, sq, 64));
        ovh[(2*16 + sq)*136 + mo] = (_Float16)(d2[2] * __shfl(i2, sq, 64));
        ovh[(3*16 + sq)*136 + mo] = (_Float16)(d2[3] * __shfl(i3, sq, 64));
        sq = 12 + rg;
        ovh[(0*16 + sq)*136 + mo] = (_Float16)(d3[0] * __shfl(i0, sq, 64));
        ovh[(1*16 + sq)*136 + mo] = (_Float16)(d3[1] * __shfl(i1, sq, 64));
        ovh[(2*16 + sq)*136 + mo] = (_Float16)(d3[2] * __shfl(i3 == i3 ? i2 : i2, sq, 64) * 0.0f + d3[2] * __shfl(i2, sq, 64));
        ovh[(3*16 + sq)*136 + mo] = (_Float16)(d3[3] * __shfl(i3, sq, 64));
    }
    __syncthreads();

    // ---- output projection via MFMA: wave handles 2 (ob,g) tiles ----
#pragma unroll
    for (int tt2 = 0; tt2 < 2; ++tt2) {
        int tl = wave * 2 + tt2;
        int ob = tl >> 2, g = tl & 3;
        f32x4 dd = {0,0,0,0};
#pragma unroll
        for (int c = 0; c < 4; ++c) {
            f16x8 wa = *(const f16x8*)(Wfrag + ((size_t)((ob * 4 + c) * 64 + lane)) * 8);
            f16x8 vb = *(const f16x8*)(ovh + (g * 16 + q15) * 136 + c * 32 + rg * 8);
            dd = __builtin_amdgcn_mfma_f32_16x16x32_f16(wa, vb, dd, 0, 0, 0);
        }
#pragma unroll
        for (int reg = 0; reg < 4; ++reg) {
            int o = ob * 16 + rg * 4 + reg;           // D row
            out[((size_t)(b * 64 + o) * 4 + g) * NPOS + qt * 16 + q15] = dd[reg] + b_out[o];
        }
    }
}

extern "C" void kernel_launch(void* const* d_in, const int* in_sizes, int n_in,
                              void* d_out, int out_size, void* d_ws, size_t ws_size,
                              hipStream_t stream)
{
    const float* x     = (const float*)d_in[0];
    const float* wq    = (const float*)d_in[1];
    const float* bq    = (const float*)d_in[2];
    const float* wk    = (const float*)d_in[3];
    const float* bk    = (const float*)d_in[4];
    const float* wv    = (const float*)d_in[5];
    const float* bv    = (const float*)d_in[6];
    const float* w_out = (const float*)d_in[7];
    const float* b_out = (const float*)d_in[8];
    const float* rw1 = (const float*)d_in[9];
    const float* rb1 = (const float*)d_in[10];
    const float* rga = (const float*)d_in[11];
    const float* rbe = (const float*)d_in[12];
    const float* rw2 = (const float*)d_in[13];
    const float* rb2 = (const float*)d_in[14];
    const float* cw1 = (const float*)d_in[15];
    const float* cb1 = (const float*)d_in[16];
    const float* cga = (const float*)d_in[17];
    const float* cbe = (const float*)d_in[18];
    const float* cw2 = (const float*)d_in[19];
    const float* cb2 = (const float*)d_in[20];
    // d_in[21]/d_in[22] (ridx/cidx) unused: closed-form rotation indices.

    float* Etr       = (float*)d_ws;                  // 880
    float* Etc       = Etr + 880;                     // 880
    _Float16* Kfrag  = (_Float16*)(Etc + 880);        // 32*49*64*8 = 802816 halves
    _Float16* Vfrag  = Kfrag + 802816;                // 32*25*64*8 = 409600
    _Float16* Wfrag  = Vfrag + 409600;                // 8192

    prep_kernel<<<418, 256, 0, stream>>>(x, wk, bk, wv, bv, w_out,
                                         rw1, rb1, rga, rbe, rw2, rb2,
                                         cw1, cb1, cga, cbe, cw2, cb2,
                                         Kfrag, Vfrag, Wfrag, Etr, Etc);
    attn_kernel<<<196, 512, 0, stream>>>(Kfrag, Vfrag, Wfrag, Etr, Etc,
                                         x, wq, bq, b_out, (float*)d_out);
}